// Round 3
// baseline (6318.871 us; speedup 1.0000x reference)
//
#include <hip/hip_runtime.h>
#include <hip/hip_bf16.h>

typedef unsigned int u32;
typedef unsigned short u16;

#define MTOT 31936      // B*N = 64*499
#define NN 499
#define BB 64

// ---------- helpers ----------
__device__ __forceinline__ float lo16(u32 u){ return __uint_as_float(u << 16); }
__device__ __forceinline__ float hi16(u32 u){ return __uint_as_float(u & 0xffff0000u); }
__device__ __forceinline__ float bf2f(u16 u){ return __uint_as_float(((u32)u) << 16); }
__device__ __forceinline__ u16 f2bf(float f){
  u32 x = __float_as_uint(f);
  u32 r = (x + 0x7fffu + ((x >> 16) & 1u)) >> 16;   // RNE
  return (u16)r;
}
__device__ __forceinline__ float sigf(float x){ return 1.f / (1.f + __expf(-x)); }
__device__ __forceinline__ float tanh_(float x){ return 2.f * sigf(2.f * x) - 1.f; }
__device__ __forceinline__ float wred(float v){
  #pragma unroll
  for (int off = 32; off; off >>= 1) v += __shfl_down(v, off, 64);
  return v;
}

typedef __attribute__((ext_vector_type(2))) __bf16 bf16x2;

// pack two f32 -> u32 of two bf16 (RNE)
#if __has_builtin(__builtin_amdgcn_cvt_pk_bf16_f32)
__device__ __forceinline__ u32 pk2bf(float a, float b){
  union { bf16x2 v; u32 u; } r;
  r.v = __builtin_amdgcn_cvt_pk_bf16_f32(a, b);
  return r.u;
}
#else
__device__ __forceinline__ u32 pk2bf(float a, float b){
  return (u32)f2bf(a) | ((u32)f2bf(b) << 16);
}
#endif

// ---------- MFMA plumbing (16x16x32 bf16) ----------
// A-frag: lane holds A[m=lane&15][k=(lane>>4)*8 + j], j=0..7  (8 bf16 = uint4)
// B-frag: lane holds B[k=(lane>>4)*8 + j][n=lane&15]
// C/D   : reg r at row=(lane>>4)*4+r, col=lane&15
typedef __attribute__((ext_vector_type(8))) short bfrag8;
typedef __attribute__((ext_vector_type(4))) float f4_t;
union FragU { uint4 u; bfrag8 s; };

__device__ __forceinline__ f4_t mfma16(FragU a, FragU b, f4_t c){
  return __builtin_amdgcn_mfma_f32_16x16x32_bf16(a.s, b.s, c, 0, 0, 0);
}

// GEMM core v2: 64M x 128N tile, 4 waves; ntBase selects this wave's 2 N-tiles.
// A (64Mx32K per kt) staged in LDS (double-buffered, one barrier/kt); B frags from global.
template <typename AL>
__device__ __forceinline__ void gemm_core2(int K32, const uint4* __restrict__ Bpack,
                                           int ntBase, f4_t (&acc)[4][2], AL aload){
  __shared__ __align__(16) uint4 As[2][256];
  const int tid = threadIdx.x;
  const int lane = tid & 63;
  const uint4* Bp0 = Bpack + ((size_t)ntBase * K32) * 64 + lane;
  const uint4* Bp1 = Bp0 + (size_t)K32 * 64;
  int buf = 0;
  for (int kt = 0; kt < K32; kt++){
    FragU b0, b1;
    b0.u = Bp0[kt * 64];
    b1.u = Bp1[kt * 64];
    As[buf][tid] = aload(kt);
    __syncthreads();
    FragU a0, a1, a2, a3;
    a0.u = As[buf][lane];
    a1.u = As[buf][64 + lane];
    a2.u = As[buf][128 + lane];
    a3.u = As[buf][192 + lane];
    acc[0][0] = mfma16(a0, b0, acc[0][0]); acc[0][1] = mfma16(a0, b1, acc[0][1]);
    acc[1][0] = mfma16(a1, b0, acc[1][0]); acc[1][1] = mfma16(a1, b1, acc[1][1]);
    acc[2][0] = mfma16(a2, b0, acc[2][0]); acc[2][1] = mfma16(a2, b1, acc[2][1]);
    acc[3][0] = mfma16(a3, b0, acc[3][0]); acc[3][1] = mfma16(a3, b1, acc[3][1]);
    buf ^= 1;
  }
}

// ---------- prep: pack weight matrix into B-fragment-layout bf16 chunks ----------
// chunk c: nt=c/(K32*64), kt=(c/64)%K32, l=c&63 -> holds B[k=kt*32+(l>>4)*8+j][n=nt*16+(l&15)]
// trans=0: B[k][n] = W[k*N+n] ; trans=1: B[k][n] = W[n*K+k]
__global__ __launch_bounds__(256) void k_packB(const float* __restrict__ W, u16* __restrict__ out,
                                               int K, int N, int trans){
  int c = blockIdx.x * 256 + threadIdx.x;
  int K32 = K >> 5;
  int total = (N >> 4) * K32 * 64;
  if (c >= total) return;
  int l = c & 63;
  int rem = c >> 6;
  int kt = rem % K32, nt = rem / K32;
  int n = nt * 16 + (l & 15);
  int kb = kt * 32 + (l >> 4) * 8;
  u32 ov[4];
  #pragma unroll
  for (int j2 = 0; j2 < 4; j2++){
    int k = kb + j2 * 2;
    float f0 = trans ? W[(size_t)n * K + k]     : W[(size_t)k * N + n];
    float f1 = trans ? W[(size_t)n * K + k + 1] : W[(size_t)(k + 1) * N + n];
    ov[j2] = pk2bf(f0, f1);
  }
  uint4 o; o.x = ov[0]; o.y = ov[1]; o.z = ov[2]; o.w = ov[3];
  *(uint4*)(out + (size_t)c * 8) = o;
}

// ---------- CSR build (chain graph, in-degree <= 3) ----------
__global__ void k_csr(const int* __restrict__ src, const int* __restrict__ dst, int E,
                      int* __restrict__ deg, int* __restrict__ insrc){
  int tid = threadIdx.x;
  for (int i = tid; i < NN; i += 256) deg[i] = 0;
  for (int i = tid; i < NN * 4; i += 256) insrc[i] = 0;
  __syncthreads();
  for (int e = tid; e < E; e += 256){
    int d = dst[e];
    int slot = atomicAdd(&deg[d], 1);
    if (slot < 4) insrc[d * 4 + slot] = src[e];
  }
}

// ---------- GEMM 1 (MFMA): x0 = concat(emb_p[p], emb_aff[aff]) @ W_affcat + b ; K=512, N=256, f32 out
__global__ __launch_bounds__(256) void k_affcat_m(
    const float* __restrict__ emb_p, const float* __restrict__ emb_aff,
    const int* __restrict__ p, const int* __restrict__ aff,
    const uint4* __restrict__ Bpack, const float* __restrict__ bias, float* __restrict__ C){
  const int tid = threadIdx.x;
  const int mBase = blockIdx.x * 64, nBase = blockIdx.y * 128;
  const int ls = tid & 63;
  const int gm = mBase + (tid >> 6) * 16 + (ls & 15);
  const int kqoff = (ls >> 4) * 8;
  const float* rp = emb_p + (size_t)p[gm] * 256 + kqoff;
  const float* ra = emb_aff + (size_t)aff[gm] * 256 + kqoff;
  f4_t acc[4][2] = {};
  gemm_core2(16, Bpack, blockIdx.y * 8 + ((tid >> 6) << 1), acc, [&](int kt) -> uint4 {
    int kb = kt * 32;
    const float* s = (kb < 256) ? (rp + kb) : (ra + kb - 256);
    float4 v0 = *(const float4*)s;
    float4 v1 = *(const float4*)(s + 4);
    uint4 o; o.x = pk2bf(v0.x, v0.y); o.y = pk2bf(v0.z, v0.w);
    o.z = pk2bf(v1.x, v1.y); o.w = pk2bf(v1.z, v1.w);
    return o;
  });
  const int wave = tid >> 6, lane = tid & 63;
  const int rb = (lane >> 4) << 2;
  const int cbase = nBase + wave * 32 + (lane & 15);
  float b0 = bias[cbase], b1 = bias[cbase + 16];
  #pragma unroll
  for (int i = 0; i < 4; i++)
    #pragma unroll
    for (int r = 0; r < 4; r++){
      int row = mBase + i * 16 + rb + r;
      C[(size_t)row * 256 + cbase]      = acc[i][0][r] + b0;
      C[(size_t)row * 256 + cbase + 16] = acc[i][1][r] + b1;
    }
}

// ---------- GEMM 2 (MFMA): h1 = x0 @ W_g1 ; K=256, N=1024, bf16 out
__global__ __launch_bounds__(256) void k_h1_m(const float* __restrict__ A,
                                              const uint4* __restrict__ Bpack,
                                              u16* __restrict__ Cb){
  const int tid = threadIdx.x;
  const int mBase = blockIdx.x * 64, nBase = blockIdx.y * 128;
  const int ls = tid & 63;
  const int gm = mBase + (tid >> 6) * 16 + (ls & 15);
  const float* ra = A + (size_t)gm * 256 + (ls >> 4) * 8;
  f4_t acc[4][2] = {};
  gemm_core2(8, Bpack, blockIdx.y * 8 + ((tid >> 6) << 1), acc, [&](int kt) -> uint4 {
    const float* s = ra + kt * 32;
    float4 v0 = *(const float4*)s;
    float4 v1 = *(const float4*)(s + 4);
    uint4 o; o.x = pk2bf(v0.x, v0.y); o.y = pk2bf(v0.z, v0.w);
    o.z = pk2bf(v1.x, v1.y); o.w = pk2bf(v1.z, v1.w);
    return o;
  });
  const int wave = tid >> 6, lane = tid & 63;
  const int rb = (lane >> 4) << 2;
  const int cbase = nBase + wave * 32 + (lane & 15);
  #pragma unroll
  for (int i = 0; i < 4; i++)
    #pragma unroll
    for (int r = 0; r < 4; r++){
      int row = mBase + i * 16 + rb + r;
      Cb[(size_t)row * 1024 + cbase]      = f2bf(acc[i][0][r]);
      Cb[(size_t)row * 1024 + cbase + 16] = f2bf(acc[i][1][r]);
    }
}

// ---------- GEMM 3 (MFMA): h2 = g1out @ W_g2 ; K=1024, N=256, f32 out ; A already bf16
__global__ __launch_bounds__(256) void k_h2_m(const u16* __restrict__ A,
                                              const uint4* __restrict__ Bpack,
                                              float* __restrict__ C){
  const int tid = threadIdx.x;
  const int mBase = blockIdx.x * 64, nBase = blockIdx.y * 128;
  const int ls = tid & 63;
  const int gm = mBase + (tid >> 6) * 16 + (ls & 15);
  const u16* ra = A + (size_t)gm * 1024 + (ls >> 4) * 8;
  f4_t acc[4][2] = {};
  gemm_core2(32, Bpack, blockIdx.y * 8 + ((tid >> 6) << 1), acc, [&](int kt) -> uint4 {
    return *(const uint4*)(ra + kt * 32);
  });
  const int wave = tid >> 6, lane = tid & 63;
  const int rb = (lane >> 4) << 2;
  const int cbase = nBase + wave * 32 + (lane & 15);
  #pragma unroll
  for (int i = 0; i < 4; i++)
    #pragma unroll
    for (int r = 0; r < 4; r++){
      int row = mBase + i * 16 + rb + r;
      C[(size_t)row * 256 + cbase]      = acc[i][0][r];
      C[(size_t)row * 256 + cbase + 16] = acc[i][1][r];
    }
}

// ---------- GEMM 4 (MFMA): gates = concat(p,q,r,x2) @ W_ih^T + bih + bhh ; K=1024, N=1024, bf16 out
// (round-0-proven structure; standard [row][1024] output layout)
__global__ __launch_bounds__(256) void k_gates_m(
    const float* __restrict__ emb_p, const float* __restrict__ emb_q, const float* __restrict__ emb_r,
    const int* __restrict__ p, const int* __restrict__ q, const int* __restrict__ r,
    const float* __restrict__ x2, const uint4* __restrict__ Bpack,
    const float* __restrict__ bih, const float* __restrict__ bhh, u16* __restrict__ Cb){
  const int tid = threadIdx.x;
  const int mBase = blockIdx.x * 64, nBase = blockIdx.y * 128;
  const int ls = tid & 63;
  const int gm = mBase + (tid >> 6) * 16 + (ls & 15);
  const int kqoff = (ls >> 4) * 8;
  const float* s0 = emb_p + (size_t)p[gm] * 256 + kqoff;
  const float* s1 = emb_q + (size_t)q[gm] * 256 + kqoff;
  const float* s2 = emb_r + (size_t)r[gm] * 256 + kqoff;
  const float* s3 = x2 + (size_t)gm * 256 + kqoff;
  f4_t acc[4][2] = {};
  gemm_core2(32, Bpack, blockIdx.y * 8 + ((tid >> 6) << 1), acc, [&](int kt) -> uint4 {
    int kb = kt * 32;
    int seg = kb >> 8, ko = kb & 255;
    const float* s = (seg == 0) ? s0 : ((seg == 1) ? s1 : ((seg == 2) ? s2 : s3));
    float4 v0 = *(const float4*)(s + ko);
    float4 v1 = *(const float4*)(s + ko + 4);
    uint4 o; o.x = pk2bf(v0.x, v0.y); o.y = pk2bf(v0.z, v0.w);
    o.z = pk2bf(v1.x, v1.y); o.w = pk2bf(v1.z, v1.w);
    return o;
  });
  const int wave = tid >> 6, lane = tid & 63;
  const int rb = (lane >> 4) << 2;
  const int cbase = nBase + wave * 32 + (lane & 15);
  float b0 = bih[cbase] + bhh[cbase];
  float b1 = bih[cbase + 16] + bhh[cbase + 16];
  #pragma unroll
  for (int i = 0; i < 4; i++)
    #pragma unroll
    for (int r2 = 0; r2 < 4; r2++){
      int row = mBase + i * 16 + rb + r2;
      Cb[(size_t)row * 1024 + cbase]      = f2bf(acc[i][0][r2] + b0);
      Cb[(size_t)row * 1024 + cbase + 16] = f2bf(acc[i][1][r2] + b1);
    }
}

// ---------- repack gates [row=b*NN+n][1024] -> LSTM stream layout ----------
// out u16 idx: ((((bg*NN+n)*8 + w)*64 + L)*32 + t*4 + rt)
//   value = gates[(bg*16 + ((L>>4)<<2) + rt)*NN + n][g*256 + w*32 + ut*16 + (L&15)]
//   with g = t&3, ut = t>>2. Block = (n, w); LDS-staged; coalesced 16B in/out.
__global__ __launch_bounds__(256) void k_repack(const u16* __restrict__ gates,
                                                u16* __restrict__ G0L){
  __shared__ __align__(16) u16 staged[64][128];
  const int tid = threadIdx.x;
  const int n = blockIdx.x, w = blockIdx.y;
  #pragma unroll
  for (int i = 0; i < 4; i++){
    const int c = tid + i * 256;           // 1024 chunks of 8 u16
    const int b = c >> 4, seg = c & 15;    // staged[b][seg*8 .. +8)
    const int t = seg >> 1, cc8 = (seg & 1) * 8;
    const int g = t & 3, ut = t >> 2;
    const u16* srcp = gates + (size_t)(b * NN + n) * 1024 + g * 256 + w * 32 + ut * 16 + cc8;
    *(uint4*)&staged[b][seg * 8] = *(const uint4*)srcp;
  }
  __syncthreads();
  const int Lt = tid >> 2, qq = tid & 3;
  const int mhi = (Lt >> 4) << 2;
  const int cc = Lt & 15;
  #pragma unroll
  for (int bg = 0; bg < 4; bg++){
    u32 vw[4];
    #pragma unroll
    for (int j = 0; j < 4; j++){
      const int t = 2 * qq + (j >> 1);
      const int r0 = (2 * j) & 3;          // 0,2,0,2
      const u16 lo = staged[bg * 16 + mhi + r0][t * 16 + cc];
      const u16 hi = staged[bg * 16 + mhi + r0 + 1][t * 16 + cc];
      vw[j] = (u32)lo | ((u32)hi << 16);
    }
    uint4 o; o.x = vw[0]; o.y = vw[1]; o.z = vw[2]; o.w = vw[3];
    *(uint4*)(G0L + ((((size_t)(bg * NN + n) * 8 + w) * 64 + Lt) * 32 + qq * 8)) = o;
  }
}

// ---------- es/ed: per (m,h) dots of h-row with a_src / a_dst ; one wave per w = m*H+h
__global__ __launch_bounds__(256) void k_esed(
    const u16* __restrict__ hb, const float* __restrict__ hf,
    const float* __restrict__ asrc, const float* __restrict__ adst,
    float* __restrict__ es, float* __restrict__ ed, int Hm1, int Fo){
  int w = blockIdx.x * 4 + (threadIdx.x >> 6);
  int lane = threadIdx.x & 63;
  int h = w & Hm1;
  size_t base = (size_t)w * Fo;
  float s = 0.f, d = 0.f;
  for (int f = lane; f < Fo; f += 64){
    float hv = hb ? bf2f(hb[base + f]) : hf[base + f];
    s += hv * asrc[h * Fo + f];
    d += hv * adst[h * Fo + f];
  }
  s = wred(s); d = wred(d);
  if (!lane){ es[w] = s; ed[w] = d; }
}

// ---------- GAT aggregation: segment softmax (deg<=3) + weighted sum + bias (+ELU)
__global__ __launch_bounds__(256) void k_gatagg(
    const u16* __restrict__ hb, const float* __restrict__ hf,
    const float* __restrict__ es, const float* __restrict__ ed,
    const int* __restrict__ deg, const int* __restrict__ insrc,
    const float* __restrict__ bias, u16* __restrict__ outb, float* __restrict__ outf,
    int H, int foShift, int HFo, int do_elu){
  int m = blockIdx.x;
  int b = m / NN;
  int n = m - b * NN;
  int dg = deg[n];
  int s0 = insrc[n * 4 + 0];
  int s1 = insrc[n * 4 + 1];
  int s2 = insrc[n * 4 + 2];
  int rowBase = b * NN;
  for (int c = threadIdx.x; c < HFo; c += 256){
    int h = c >> foShift;
    float edv = ed[(size_t)m * H + h];
    float sc0 = es[(size_t)(rowBase + s0) * H + h] + edv;
    sc0 = (sc0 >= 0.f) ? sc0 : 0.2f * sc0;
    float sc1 = 0.f, sc2 = 0.f, mx = sc0;
    if (dg > 1){ sc1 = es[(size_t)(rowBase + s1) * H + h] + edv; sc1 = (sc1 >= 0.f) ? sc1 : 0.2f * sc1; mx = fmaxf(mx, sc1); }
    if (dg > 2){ sc2 = es[(size_t)(rowBase + s2) * H + h] + edv; sc2 = (sc2 >= 0.f) ? sc2 : 0.2f * sc2; mx = fmaxf(mx, sc2); }
    float e0 = __expf(sc0 - mx), e1 = 0.f, e2 = 0.f;
    if (dg > 1) e1 = __expf(sc1 - mx);
    if (dg > 2) e2 = __expf(sc2 - mx);
    float inv = 1.f / (e0 + e1 + e2);
    size_t c0 = (size_t)(rowBase + s0) * HFo + c;
    float acc = e0 * (hb ? bf2f(hb[c0]) : hf[c0]);
    if (dg > 1){ size_t c1 = (size_t)(rowBase + s1) * HFo + c; acc += e1 * (hb ? bf2f(hb[c1]) : hf[c1]); }
    if (dg > 2){ size_t c2 = (size_t)(rowBase + s2) * HFo + c; acc += e2 * (hb ? bf2f(hb[c2]) : hf[c2]); }
    acc *= inv;
    float o = acc + bias[c];
    if (do_elu) o = (o > 0.f) ? o : (__expf(o) - 1.f);
    if (outb) outb[(size_t)m * HFo + c] = f2bf(o);
    else      outf[(size_t)m * HFo + c] = o;
  }
}

// ---------- LSTM recurrence v13 (MFMA, barrier-synced, L2-streamed weights) ----------
// Same structure as v12 (VERIFIED CORRECT in round 2) with two changes:
//  (1) amdgpu_waves_per_eu(2,2): 512 thr = 2 waves/EU -> 256-VGPR budget. v12
//      compiled at 128 VGPRs and spilled the weight ring to scratch (the 5x).
//  (2) A-frags double-buffered (a_cur/a_nxt, ds_read issued one phase ahead)
//      instead of holding all 8: demand ~205 VGPRs, headroom under the cap.
__global__ __launch_bounds__(512)
__attribute__((amdgpu_waves_per_eu(2, 2)))
void k_lstm(const u16* __restrict__ g0l,      // gates in k_repack layout
            const uint4* __restrict__ bph,    // packed W_hh^T B-frags (K=256,N=1024)
            float* __restrict__ h_all){
  __shared__ __align__(16) u16 hsh[2][4096];   // 16 KB double-buffered h
  const int bg = blockIdx.x, tid = threadIdx.x;
  const int w = tid >> 6, lane = tid & 63;
  const int am = lane & 15, oct = lane >> 4;
  const int hm = oct << 2, uc = am;
  const u32 abNos = (u32)(am * 512 + oct * 16);
  const u32 sw = (u32)((am & 7) << 4);
  ((uint4*)hsh[1])[tid] = make_uint4(0u, 0u, 0u, 0u);   // h(-1) = 0

  // per-t weight stream base pointers: frag (t, group g) at wp[t] + g*64
  const uint4* wp[8];
  #pragma unroll
  for (int t = 0; t < 8; t++){
    const int nt = (t & 3) * 16 + w * 2 + (t >> 2);
    wp[t] = bph + (size_t)(nt * 8) * 64 + lane;
  }
  // prologue: fill ring slots with groups 0,1,2
  uint4 wbuf[3][8];
  #pragma unroll
  for (int s = 0; s < 3; s++)
    #pragma unroll
    for (int t = 0; t < 8; t++) wbuf[s][t] = wp[t][s * 64];

  const uint4* g0p = (const uint4*)g0l + ((size_t)((size_t)bg * NN * 8 + w) * 64 + lane) * 4;
  uint4 G0q[4];
  G0q[0] = g0p[0]; G0q[1] = g0p[1]; G0q[2] = g0p[2]; G0q[3] = g0p[3];
  g0p += 2048;

  const size_t hofs0 = ((size_t)(bg * 16 + hm) * NN) * 256 + (size_t)w * 32 + uc;
  float cst[8] = {0.f, 0.f, 0.f, 0.f, 0.f, 0.f, 0.f, 0.f};
  __syncthreads();

  #pragma unroll 1
  for (int n = 0; n < NN; n++){
    const char* hrd = (const char*)hsh[(n + 1) & 1];   // h(n-1)
    char* hwr = (char*)hsh[n & 1];                     // h(n)
    f4_t acc[8] = {};
    // A-frag double buffer: read kc=pp+1 during phase pp (swizzled ds_read_b128)
    FragU a_cur, a_nxt;
    a_cur.u = *(const uint4*)(hrd + ((abNos + 0u) ^ sw));
    // 8 phases: consume ring slot, 8 MFMAs, reissue slot for its next use
    #pragma unroll
    for (int pp = 0; pp < 8; pp++){
      if (pp < 7)
        a_nxt.u = *(const uint4*)(hrd + ((abNos + (u32)((pp + 1) * 64)) ^ sw));
      const int slot = pp % 3;
      const int gnext = (pp + 3 < 8) ? (pp + 3) : slot;   // next group this slot serves
      #pragma unroll
      for (int t = 0; t < 8; t++){
        FragU b; b.u = wbuf[slot][t];
        acc[t] = mfma16(a_cur, b, acc[t]);
      }
      #pragma unroll
      for (int t = 0; t < 8; t++) wbuf[slot][t] = wp[t][gnext * 64];
      a_cur = a_nxt;
    }
    // gate math: lane owns (m = hm+rr, u = w*32+ut*16+uc); i/f/g/o in acc[ut*4+g]
    #pragma unroll
    for (int ut = 0; ut < 2; ut++){
      #pragma unroll
      for (int rr = 0; rr < 4; rr++){
        float gv[4];
        #pragma unroll
        for (int g = 0; g < 4; g++){
          const int t = ut * 4 + g;
          const uint4 qv = G0q[t >> 1];
          const int wi = ((t & 1) << 1) + (rr >> 1);
          const u32 uw = (wi == 0) ? qv.x : (wi == 1) ? qv.y : (wi == 2) ? qv.z : qv.w;
          gv[g] = acc[t][rr] + ((rr & 1) ? hi16(uw) : lo16(uw));
        }
        const int ci = ut * 4 + rr;
        const float cv = sigf(gv[1]) * cst[ci] + sigf(gv[0]) * tanh_(gv[2]);
        cst[ci] = cv;
        const float hv = sigf(gv[3]) * tanh_(cv);
        const int mm = hm + rr;
        const u32 wb = ((u32)(mm * 512 + (w * 32 + ut * 16 + uc) * 2)) ^ ((u32)(mm & 7) << 4);
        *(u16*)(hwr + wb) = f2bf(hv);
        h_all[hofs0 + (size_t)rr * (NN * 256) + (size_t)n * 256 + ut * 16] = hv;
      }
    }
    // issue next step's gate loads (consumed one full step later)
    if (n + 1 < NN){
      G0q[0] = g0p[0]; G0q[1] = g0p[1]; G0q[2] = g0p[2]; G0q[3] = g0p[3];
      g0p += 2048;
    }
    // publish h(n): drain LDS ops, barrier (no vmcnt drain), fence scheduling
    asm volatile("s_waitcnt lgkmcnt(0)" ::: "memory");
    __builtin_amdgcn_s_barrier();
    __builtin_amdgcn_sched_barrier(0);
  }
}

// ---------- final: y = sigmoid(concat(h, qn_emb, pn_emb) @ W_out + b_out) ; one wave per row
__global__ __launch_bounds__(256) void k_out(const float* __restrict__ h_all,
    const float* __restrict__ emb_q, const float* __restrict__ emb_p,
    const int* __restrict__ qn, const int* __restrict__ pn,
    const float* __restrict__ Wo, const float* __restrict__ bo, float* __restrict__ y){
  int m = blockIdx.x * 4 + (threadIdx.x >> 6);
  int lane = threadIdx.x & 63;
  const float* hr = h_all + (size_t)m * 256;
  const float* rq = emb_q + (size_t)qn[m] * 256;
  const float* rp = emb_p + (size_t)pn[m] * 256;
  float acc = 0.f;
  #pragma unroll
  for (int f = 0; f < 256; f += 64){
    int d = f + lane;
    acc += hr[d] * Wo[d];
    acc += rq[d] * Wo[256 + d];
    acc += rp[d] * Wo[512 + d];
  }
  acc = wred(acc);
  if (!lane) y[m] = sigf(acc + bo[0]);
}

// ---------- launch ----------
extern "C" void kernel_launch(void* const* d_in, const int* in_sizes, int n_in,
                              void* d_out, int out_size, void* d_ws, size_t ws_size,
                              hipStream_t stream){
  (void)n_in; (void)out_size; (void)ws_size;
  const int* p    = (const int*)d_in[1];
  const int* q    = (const int*)d_in[2];
  const int* r    = (const int*)d_in[3];
  const int* aff  = (const int*)d_in[4];
  const int* qn   = (const int*)d_in[5];
  const int* pn   = (const int*)d_in[6];
  const int* src  = (const int*)d_in[7];
  const int* dst  = (const int*)d_in[8];
  const float* emb_p  = (const float*)d_in[9];
  const float* emb_q  = (const float*)d_in[10];
  const float* emb_r  = (const float*)d_in[11];
  const float* emb_aff= (const float*)d_in[12];
  const float* W_aff  = (const float*)d_in[13];
  const float* b_aff  = (const float*)d_in[14];
  const float* W_g1   = (const float*)d_in[15];
  const float* a_s1   = (const float*)d_in[16];
  const float* a_d1   = (const float*)d_in[17];
  const float* b_g1   = (const float*)d_in[18];
  const float* W_g2   = (const float*)d_in[19];
  const float* a_s2   = (const float*)d_in[20];
  const float* a_d2   = (const float*)d_in[21];
  const float* b_g2   = (const float*)d_in[22];
  const float* W_ih   = (const float*)d_in[23];
  const float* W_hh   = (const float*)d_in[24];
  const float* b_ih   = (const float*)d_in[25];
  const float* b_hh   = (const float*)d_in[26];
  const float* W_out  = (const float*)d_in[27];
  const float* b_out  = (const float*)d_in[28];
  const int E = in_sizes[7];

  char* ws = (char*)d_ws;
  size_t off = 0;
  auto alloc = [&](size_t bytes){ size_t ret = off; off += (bytes + 255) & ~(size_t)255; return ret; };
  size_t o_bigA = alloc((size_t)MTOT * 1024 * 2);   // h1 bf16 -> gates bf16 (row layout)
  size_t o_bigB = alloc((size_t)MTOT * 1024 * 2);   // g1out bf16 -> x2 f32 -> G0L (lstm layout)
  size_t o_buf3 = alloc((size_t)MTOT * 256 * 4);    // x0 -> h2 -> h_all
  size_t o_es1 = alloc((size_t)MTOT * 8 * 4);
  size_t o_ed1 = alloc((size_t)MTOT * 8 * 4);
  size_t o_es2 = alloc((size_t)MTOT * 4);
  size_t o_ed2 = alloc((size_t)MTOT * 4);
  size_t o_whh = alloc((size_t)32768 * 16);      // W_hh^T B-frag pack (K=256,N=1024)
  size_t o_deg = alloc(512 * 4);
  size_t o_ins = alloc((size_t)NN * 4 * 4);
  size_t o_bpih  = alloc((size_t)131072 * 16);   // W_ih^T pack (K=1024,N=1024)
  size_t o_bpg1  = alloc((size_t)32768 * 16);    // W_g1 pack (K=256,N=1024)
  size_t o_bpg2  = alloc((size_t)32768 * 16);    // W_g2 pack (K=1024,N=256)
  size_t o_bpaff = alloc((size_t)16384 * 16);    // W_affcat pack (K=512,N=256)

  u16*   h1    = (u16*)(ws + o_bigA);
  u16*   gates = (u16*)(ws + o_bigA);
  u16*   g1out = (u16*)(ws + o_bigB);
  float* x2    = (float*)(ws + o_bigB);
  u16*   G0L   = (u16*)(ws + o_bigB);
  float* x0    = (float*)(ws + o_buf3);
  float* h2    = (float*)(ws + o_buf3);
  float* h_all = (float*)(ws + o_buf3);
  float* es1   = (float*)(ws + o_es1);
  float* ed1   = (float*)(ws + o_ed1);
  float* es2   = (float*)(ws + o_es2);
  float* ed2   = (float*)(ws + o_ed2);
  u16*   bphh  = (u16*)(ws + o_whh);
  int*   degp  = (int*)(ws + o_deg);
  int*   insp  = (int*)(ws + o_ins);
  u16*   bpih  = (u16*)(ws + o_bpih);
  u16*   bpg1  = (u16*)(ws + o_bpg1);
  u16*   bpg2  = (u16*)(ws + o_bpg2);
  u16*   bpaff = (u16*)(ws + o_bpaff);

  k_csr<<<1, 256, 0, stream>>>(src, dst, E, degp, insp);
  k_packB<<<128, 256, 0, stream>>>(W_hh, bphh, 256, 1024, 1);
  k_packB<<<512, 256, 0, stream>>>(W_ih, bpih, 1024, 1024, 1);
  k_packB<<<128, 256, 0, stream>>>(W_g1, bpg1, 256, 1024, 0);
  k_packB<<<128, 256, 0, stream>>>(W_g2, bpg2, 1024, 256, 0);
  k_packB<<<64, 256, 0, stream>>>(W_aff, bpaff, 512, 256, 0);

  k_affcat_m<<<dim3(NN, 2), 256, 0, stream>>>(emb_p, emb_aff, p, aff,
                                              (const uint4*)bpaff, b_aff, x0);
  k_h1_m<<<dim3(NN, 8), 256, 0, stream>>>(x0, (const uint4*)bpg1, h1);
  k_esed<<<(MTOT * 8) / 4, 256, 0, stream>>>(h1, nullptr, a_s1, a_d1, es1, ed1, 7, 128);
  k_gatagg<<<MTOT, 256, 0, stream>>>(h1, nullptr, es1, ed1, degp, insp, b_g1,
                                     g1out, nullptr, 8, 7, 1024, 1);
  k_h2_m<<<dim3(NN, 2), 256, 0, stream>>>(g1out, (const uint4*)bpg2, h2);
  k_esed<<<MTOT / 4, 256, 0, stream>>>(nullptr, h2, a_s2, a_d2, es2, ed2, 0, 256);
  k_gatagg<<<MTOT, 256, 0, stream>>>(nullptr, h2, es2, ed2, degp, insp, b_g2,
                                     nullptr, x2, 1, 8, 256, 0);
  k_gates_m<<<dim3(NN, 8), 256, 0, stream>>>(emb_p, emb_q, emb_r, p, q, r, x2,
                                             (const uint4*)bpih, b_ih, b_hh, gates);
  k_repack<<<dim3(NN, 8), 256, 0, stream>>>(gates, G0L);
  k_lstm<<<4, 512, 0, stream>>>(G0L, (const uint4*)bphh, h_all);
  k_out<<<MTOT / 4, 256, 0, stream>>>(h_all, emb_q, emb_p, qn, pn, W_out, b_out, (float*)d_out);
}

// Round 5
// 3115.724 us; speedup vs baseline: 2.0281x; 2.0281x over previous
//
#include <hip/hip_runtime.h>
#include <hip/hip_bf16.h>

typedef unsigned int u32;
typedef unsigned short u16;

#define MTOT 31936      // B*N = 64*499
#define NN 499
#define BB 64

// ---------- helpers ----------
__device__ __forceinline__ float lo16(u32 u){ return __uint_as_float(u << 16); }
__device__ __forceinline__ float hi16(u32 u){ return __uint_as_float(u & 0xffff0000u); }
__device__ __forceinline__ float bf2f(u16 u){ return __uint_as_float(((u32)u) << 16); }
__device__ __forceinline__ u16 f2bf(float f){
  u32 x = __float_as_uint(f);
  u32 r = (x + 0x7fffu + ((x >> 16) & 1u)) >> 16;   // RNE
  return (u16)r;
}
__device__ __forceinline__ float sigf(float x){ return 1.f / (1.f + __expf(-x)); }
__device__ __forceinline__ float tanh_(float x){ return 2.f * sigf(2.f * x) - 1.f; }
__device__ __forceinline__ float wred(float v){
  #pragma unroll
  for (int off = 32; off; off >>= 1) v += __shfl_down(v, off, 64);
  return v;
}

typedef __attribute__((ext_vector_type(2))) __bf16 bf16x2;

// pack two f32 -> u32 of two bf16 (RNE)
#if __has_builtin(__builtin_amdgcn_cvt_pk_bf16_f32)
__device__ __forceinline__ u32 pk2bf(float a, float b){
  union { bf16x2 v; u32 u; } r;
  r.v = __builtin_amdgcn_cvt_pk_bf16_f32(a, b);
  return r.u;
}
#else
__device__ __forceinline__ u32 pk2bf(float a, float b){
  return (u32)f2bf(a) | ((u32)f2bf(b) << 16);
}
#endif

// ---------- MFMA plumbing (16x16x32 bf16) ----------
// A-frag: lane holds A[m=lane&15][k=(lane>>4)*8 + j], j=0..7  (8 bf16 = uint4)
// B-frag: lane holds B[k=(lane>>4)*8 + j][n=lane&15]
// C/D   : reg r at row=(lane>>4)*4+r, col=lane&15
typedef __attribute__((ext_vector_type(8))) short bfrag8;
typedef __attribute__((ext_vector_type(4))) float f4_t;
union FragU { uint4 u; bfrag8 s; };

__device__ __forceinline__ f4_t mfma16(FragU a, FragU b, f4_t c){
  return __builtin_amdgcn_mfma_f32_16x16x32_bf16(a.s, b.s, c, 0, 0, 0);
}

// GEMM core v2: 64M x 128N tile, 4 waves; ntBase selects this wave's 2 N-tiles.
// A (64Mx32K per kt) staged in LDS (double-buffered, one barrier/kt); B frags from global.
template <typename AL>
__device__ __forceinline__ void gemm_core2(int K32, const uint4* __restrict__ Bpack,
                                           int ntBase, f4_t (&acc)[4][2], AL aload){
  __shared__ __align__(16) uint4 As[2][256];
  const int tid = threadIdx.x;
  const int lane = tid & 63;
  const uint4* Bp0 = Bpack + ((size_t)ntBase * K32) * 64 + lane;
  const uint4* Bp1 = Bp0 + (size_t)K32 * 64;
  int buf = 0;
  for (int kt = 0; kt < K32; kt++){
    FragU b0, b1;
    b0.u = Bp0[kt * 64];
    b1.u = Bp1[kt * 64];
    As[buf][tid] = aload(kt);
    __syncthreads();
    FragU a0, a1, a2, a3;
    a0.u = As[buf][lane];
    a1.u = As[buf][64 + lane];
    a2.u = As[buf][128 + lane];
    a3.u = As[buf][192 + lane];
    acc[0][0] = mfma16(a0, b0, acc[0][0]); acc[0][1] = mfma16(a0, b1, acc[0][1]);
    acc[1][0] = mfma16(a1, b0, acc[1][0]); acc[1][1] = mfma16(a1, b1, acc[1][1]);
    acc[2][0] = mfma16(a2, b0, acc[2][0]); acc[2][1] = mfma16(a2, b1, acc[2][1]);
    acc[3][0] = mfma16(a3, b0, acc[3][0]); acc[3][1] = mfma16(a3, b1, acc[3][1]);
    buf ^= 1;
  }
}

// ---------- prep: pack weight matrix into B-fragment-layout bf16 chunks ----------
// chunk c: nt=c/(K32*64), kt=(c/64)%K32, l=c&63 -> holds B[k=kt*32+(l>>4)*8+j][n=nt*16+(l&15)]
// trans=0: B[k][n] = W[k*N+n] ; trans=1: B[k][n] = W[n*K+k]
__global__ __launch_bounds__(256) void k_packB(const float* __restrict__ W, u16* __restrict__ out,
                                               int K, int N, int trans){
  int c = blockIdx.x * 256 + threadIdx.x;
  int K32 = K >> 5;
  int total = (N >> 4) * K32 * 64;
  if (c >= total) return;
  int l = c & 63;
  int rem = c >> 6;
  int kt = rem % K32, nt = rem / K32;
  int n = nt * 16 + (l & 15);
  int kb = kt * 32 + (l >> 4) * 8;
  u32 ov[4];
  #pragma unroll
  for (int j2 = 0; j2 < 4; j2++){
    int k = kb + j2 * 2;
    float f0 = trans ? W[(size_t)n * K + k]     : W[(size_t)k * N + n];
    float f1 = trans ? W[(size_t)n * K + k + 1] : W[(size_t)(k + 1) * N + n];
    ov[j2] = pk2bf(f0, f1);
  }
  uint4 o; o.x = ov[0]; o.y = ov[1]; o.z = ov[2]; o.w = ov[3];
  *(uint4*)(out + (size_t)c * 8) = o;
}

// ---------- CSR build (chain graph, in-degree <= 3) ----------
__global__ void k_csr(const int* __restrict__ src, const int* __restrict__ dst, int E,
                      int* __restrict__ deg, int* __restrict__ insrc){
  int tid = threadIdx.x;
  for (int i = tid; i < NN; i += 256) deg[i] = 0;
  for (int i = tid; i < NN * 4; i += 256) insrc[i] = 0;
  __syncthreads();
  for (int e = tid; e < E; e += 256){
    int d = dst[e];
    int slot = atomicAdd(&deg[d], 1);
    if (slot < 4) insrc[d * 4 + slot] = src[e];
  }
}

// ---------- GEMM 1 (MFMA): x0 = concat(emb_p[p], emb_aff[aff]) @ W_affcat + b ; K=512, N=256, f32 out
__global__ __launch_bounds__(256) void k_affcat_m(
    const float* __restrict__ emb_p, const float* __restrict__ emb_aff,
    const int* __restrict__ p, const int* __restrict__ aff,
    const uint4* __restrict__ Bpack, const float* __restrict__ bias, float* __restrict__ C){
  const int tid = threadIdx.x;
  const int mBase = blockIdx.x * 64, nBase = blockIdx.y * 128;
  const int ls = tid & 63;
  const int gm = mBase + (tid >> 6) * 16 + (ls & 15);
  const int kqoff = (ls >> 4) * 8;
  const float* rp = emb_p + (size_t)p[gm] * 256 + kqoff;
  const float* ra = emb_aff + (size_t)aff[gm] * 256 + kqoff;
  f4_t acc[4][2] = {};
  gemm_core2(16, Bpack, blockIdx.y * 8 + ((tid >> 6) << 1), acc, [&](int kt) -> uint4 {
    int kb = kt * 32;
    const float* s = (kb < 256) ? (rp + kb) : (ra + kb - 256);
    float4 v0 = *(const float4*)s;
    float4 v1 = *(const float4*)(s + 4);
    uint4 o; o.x = pk2bf(v0.x, v0.y); o.y = pk2bf(v0.z, v0.w);
    o.z = pk2bf(v1.x, v1.y); o.w = pk2bf(v1.z, v1.w);
    return o;
  });
  const int wave = tid >> 6, lane = tid & 63;
  const int rb = (lane >> 4) << 2;
  const int cbase = nBase + wave * 32 + (lane & 15);
  float b0 = bias[cbase], b1 = bias[cbase + 16];
  #pragma unroll
  for (int i = 0; i < 4; i++)
    #pragma unroll
    for (int r = 0; r < 4; r++){
      int row = mBase + i * 16 + rb + r;
      C[(size_t)row * 256 + cbase]      = acc[i][0][r] + b0;
      C[(size_t)row * 256 + cbase + 16] = acc[i][1][r] + b1;
    }
}

// ---------- GEMM 2 (MFMA): h1 = x0 @ W_g1 ; K=256, N=1024, bf16 out
__global__ __launch_bounds__(256) void k_h1_m(const float* __restrict__ A,
                                              const uint4* __restrict__ Bpack,
                                              u16* __restrict__ Cb){
  const int tid = threadIdx.x;
  const int mBase = blockIdx.x * 64, nBase = blockIdx.y * 128;
  const int ls = tid & 63;
  const int gm = mBase + (tid >> 6) * 16 + (ls & 15);
  const float* ra = A + (size_t)gm * 256 + (ls >> 4) * 8;
  f4_t acc[4][2] = {};
  gemm_core2(8, Bpack, blockIdx.y * 8 + ((tid >> 6) << 1), acc, [&](int kt) -> uint4 {
    const float* s = ra + kt * 32;
    float4 v0 = *(const float4*)s;
    float4 v1 = *(const float4*)(s + 4);
    uint4 o; o.x = pk2bf(v0.x, v0.y); o.y = pk2bf(v0.z, v0.w);
    o.z = pk2bf(v1.x, v1.y); o.w = pk2bf(v1.z, v1.w);
    return o;
  });
  const int wave = tid >> 6, lane = tid & 63;
  const int rb = (lane >> 4) << 2;
  const int cbase = nBase + wave * 32 + (lane & 15);
  #pragma unroll
  for (int i = 0; i < 4; i++)
    #pragma unroll
    for (int r = 0; r < 4; r++){
      int row = mBase + i * 16 + rb + r;
      Cb[(size_t)row * 1024 + cbase]      = f2bf(acc[i][0][r]);
      Cb[(size_t)row * 1024 + cbase + 16] = f2bf(acc[i][1][r]);
    }
}

// ---------- GEMM 3 (MFMA): h2 = g1out @ W_g2 ; K=1024, N=256, f32 out ; A already bf16
__global__ __launch_bounds__(256) void k_h2_m(const u16* __restrict__ A,
                                              const uint4* __restrict__ Bpack,
                                              float* __restrict__ C){
  const int tid = threadIdx.x;
  const int mBase = blockIdx.x * 64, nBase = blockIdx.y * 128;
  const int ls = tid & 63;
  const int gm = mBase + (tid >> 6) * 16 + (ls & 15);
  const u16* ra = A + (size_t)gm * 1024 + (ls >> 4) * 8;
  f4_t acc[4][2] = {};
  gemm_core2(32, Bpack, blockIdx.y * 8 + ((tid >> 6) << 1), acc, [&](int kt) -> uint4 {
    return *(const uint4*)(ra + kt * 32);
  });
  const int wave = tid >> 6, lane = tid & 63;
  const int rb = (lane >> 4) << 2;
  const int cbase = nBase + wave * 32 + (lane & 15);
  #pragma unroll
  for (int i = 0; i < 4; i++)
    #pragma unroll
    for (int r = 0; r < 4; r++){
      int row = mBase + i * 16 + rb + r;
      C[(size_t)row * 256 + cbase]      = acc[i][0][r];
      C[(size_t)row * 256 + cbase + 16] = acc[i][1][r];
    }
}

// ---------- GEMM 4 (MFMA): gates = concat(p,q,r,x2) @ W_ih^T + bih + bhh ; K=1024, N=1024, bf16 out
// (round-0-proven structure; standard [row][1024] output layout)
__global__ __launch_bounds__(256) void k_gates_m(
    const float* __restrict__ emb_p, const float* __restrict__ emb_q, const float* __restrict__ emb_r,
    const int* __restrict__ p, const int* __restrict__ q, const int* __restrict__ r,
    const float* __restrict__ x2, const uint4* __restrict__ Bpack,
    const float* __restrict__ bih, const float* __restrict__ bhh, u16* __restrict__ Cb){
  const int tid = threadIdx.x;
  const int mBase = blockIdx.x * 64, nBase = blockIdx.y * 128;
  const int ls = tid & 63;
  const int gm = mBase + (tid >> 6) * 16 + (ls & 15);
  const int kqoff = (ls >> 4) * 8;
  const float* s0 = emb_p + (size_t)p[gm] * 256 + kqoff;
  const float* s1 = emb_q + (size_t)q[gm] * 256 + kqoff;
  const float* s2 = emb_r + (size_t)r[gm] * 256 + kqoff;
  const float* s3 = x2 + (size_t)gm * 256 + kqoff;
  f4_t acc[4][2] = {};
  gemm_core2(32, Bpack, blockIdx.y * 8 + ((tid >> 6) << 1), acc, [&](int kt) -> uint4 {
    int kb = kt * 32;
    int seg = kb >> 8, ko = kb & 255;
    const float* s = (seg == 0) ? s0 : ((seg == 1) ? s1 : ((seg == 2) ? s2 : s3));
    float4 v0 = *(const float4*)(s + ko);
    float4 v1 = *(const float4*)(s + ko + 4);
    uint4 o; o.x = pk2bf(v0.x, v0.y); o.y = pk2bf(v0.z, v0.w);
    o.z = pk2bf(v1.x, v1.y); o.w = pk2bf(v1.z, v1.w);
    return o;
  });
  const int wave = tid >> 6, lane = tid & 63;
  const int rb = (lane >> 4) << 2;
  const int cbase = nBase + wave * 32 + (lane & 15);
  float b0 = bih[cbase] + bhh[cbase];
  float b1 = bih[cbase + 16] + bhh[cbase + 16];
  #pragma unroll
  for (int i = 0; i < 4; i++)
    #pragma unroll
    for (int r2 = 0; r2 < 4; r2++){
      int row = mBase + i * 16 + rb + r2;
      Cb[(size_t)row * 1024 + cbase]      = f2bf(acc[i][0][r2] + b0);
      Cb[(size_t)row * 1024 + cbase + 16] = f2bf(acc[i][1][r2] + b1);
    }
}

// ---------- repack gates [row=b*NN+n][1024] -> LSTM stream layout ----------
// out u16 idx: ((((bg*NN+n)*8 + w)*64 + L)*32 + t*4 + rt)
//   value = gates[(bg*16 + ((L>>4)<<2) + rt)*NN + n][g*256 + w*32 + ut*16 + (L&15)]
//   with g = t&3, ut = t>>2. Block = (n, w); LDS-staged; coalesced 16B in/out.
__global__ __launch_bounds__(256) void k_repack(const u16* __restrict__ gates,
                                                u16* __restrict__ G0L){
  __shared__ __align__(16) u16 staged[64][128];
  const int tid = threadIdx.x;
  const int n = blockIdx.x, w = blockIdx.y;
  #pragma unroll
  for (int i = 0; i < 4; i++){
    const int c = tid + i * 256;           // 1024 chunks of 8 u16
    const int b = c >> 4, seg = c & 15;    // staged[b][seg*8 .. +8)
    const int t = seg >> 1, cc8 = (seg & 1) * 8;
    const int g = t & 3, ut = t >> 2;
    const u16* srcp = gates + (size_t)(b * NN + n) * 1024 + g * 256 + w * 32 + ut * 16 + cc8;
    *(uint4*)&staged[b][seg * 8] = *(const uint4*)srcp;
  }
  __syncthreads();
  const int Lt = tid >> 2, qq = tid & 3;
  const int mhi = (Lt >> 4) << 2;
  const int cc = Lt & 15;
  #pragma unroll
  for (int bg = 0; bg < 4; bg++){
    u32 vw[4];
    #pragma unroll
    for (int j = 0; j < 4; j++){
      const int t = 2 * qq + (j >> 1);
      const int r0 = (2 * j) & 3;          // 0,2,0,2
      const u16 lo = staged[bg * 16 + mhi + r0][t * 16 + cc];
      const u16 hi = staged[bg * 16 + mhi + r0 + 1][t * 16 + cc];
      vw[j] = (u32)lo | ((u32)hi << 16);
    }
    uint4 o; o.x = vw[0]; o.y = vw[1]; o.z = vw[2]; o.w = vw[3];
    *(uint4*)(G0L + ((((size_t)(bg * NN + n) * 8 + w) * 64 + Lt) * 32 + qq * 8)) = o;
  }
}

// ---------- es/ed: per (m,h) dots of h-row with a_src / a_dst ; one wave per w = m*H+h
__global__ __launch_bounds__(256) void k_esed(
    const u16* __restrict__ hb, const float* __restrict__ hf,
    const float* __restrict__ asrc, const float* __restrict__ adst,
    float* __restrict__ es, float* __restrict__ ed, int Hm1, int Fo){
  int w = blockIdx.x * 4 + (threadIdx.x >> 6);
  int lane = threadIdx.x & 63;
  int h = w & Hm1;
  size_t base = (size_t)w * Fo;
  float s = 0.f, d = 0.f;
  for (int f = lane; f < Fo; f += 64){
    float hv = hb ? bf2f(hb[base + f]) : hf[base + f];
    s += hv * asrc[h * Fo + f];
    d += hv * adst[h * Fo + f];
  }
  s = wred(s); d = wred(d);
  if (!lane){ es[w] = s; ed[w] = d; }
}

// ---------- GAT aggregation: segment softmax (deg<=3) + weighted sum + bias (+ELU)
__global__ __launch_bounds__(256) void k_gatagg(
    const u16* __restrict__ hb, const float* __restrict__ hf,
    const float* __restrict__ es, const float* __restrict__ ed,
    const int* __restrict__ deg, const int* __restrict__ insrc,
    const float* __restrict__ bias, u16* __restrict__ outb, float* __restrict__ outf,
    int H, int foShift, int HFo, int do_elu){
  int m = blockIdx.x;
  int b = m / NN;
  int n = m - b * NN;
  int dg = deg[n];
  int s0 = insrc[n * 4 + 0];
  int s1 = insrc[n * 4 + 1];
  int s2 = insrc[n * 4 + 2];
  int rowBase = b * NN;
  for (int c = threadIdx.x; c < HFo; c += 256){
    int h = c >> foShift;
    float edv = ed[(size_t)m * H + h];
    float sc0 = es[(size_t)(rowBase + s0) * H + h] + edv;
    sc0 = (sc0 >= 0.f) ? sc0 : 0.2f * sc0;
    float sc1 = 0.f, sc2 = 0.f, mx = sc0;
    if (dg > 1){ sc1 = es[(size_t)(rowBase + s1) * H + h] + edv; sc1 = (sc1 >= 0.f) ? sc1 : 0.2f * sc1; mx = fmaxf(mx, sc1); }
    if (dg > 2){ sc2 = es[(size_t)(rowBase + s2) * H + h] + edv; sc2 = (sc2 >= 0.f) ? sc2 : 0.2f * sc2; mx = fmaxf(mx, sc2); }
    float e0 = __expf(sc0 - mx), e1 = 0.f, e2 = 0.f;
    if (dg > 1) e1 = __expf(sc1 - mx);
    if (dg > 2) e2 = __expf(sc2 - mx);
    float inv = 1.f / (e0 + e1 + e2);
    size_t c0 = (size_t)(rowBase + s0) * HFo + c;
    float acc = e0 * (hb ? bf2f(hb[c0]) : hf[c0]);
    if (dg > 1){ size_t c1 = (size_t)(rowBase + s1) * HFo + c; acc += e1 * (hb ? bf2f(hb[c1]) : hf[c1]); }
    if (dg > 2){ size_t c2 = (size_t)(rowBase + s2) * HFo + c; acc += e2 * (hb ? bf2f(hb[c2]) : hf[c2]); }
    acc *= inv;
    float o = acc + bias[c];
    if (do_elu) o = (o > 0.f) ? o : (__expf(o) - 1.f);
    if (outb) outb[(size_t)m * HFo + c] = f2bf(o);
    else      outf[(size_t)m * HFo + c] = o;
  }
}

// ---------- LSTM recurrence v15 (MFMA, CU-RESIDENT weights, 2-pass) ----------
// v14 design, but with the attribute combo that is PROVEN to run on this
// harness (v13): __launch_bounds__(512) + amdgpu_waves_per_eu(2,2). v14's
// untested __launch_bounds__(512,2) is the prime suspect for the round-4
// container death (if arg2 is handled CUDA-style as min-BLOCKS/SM=2, then
// 2 x 155648B LDS > 160KB is unsatisfiable).
// Design: weights CU-resident. Each wave's 64 B-frags: 47 in regs (188 VGPR)
// + 17 in per-wave LDS (8x17KB=136KB + 16KB h = 152KB LDS -> 1 block/CU,
// which also pins the compiler's occupancy view at 2 waves/EU -> 256-reg cap).
// Step = TWO PASSES (ut=0/1), each acc[4] over 8 k-phases then gate math.
// Sync: one lgkmcnt(0) + raw s_barrier + sched_barrier(0) per step (proven).
// Gate prefetch G0q issued at end of step n-1 (1-step lead > HBM latency).
#define WREG 47
#define WLDS 17
__global__ __launch_bounds__(512)
__attribute__((amdgpu_waves_per_eu(2, 2)))
void k_lstm(const u16* __restrict__ g0l,      // gates in k_repack layout
            const uint4* __restrict__ bph,    // packed W_hh^T B-frags (K=256,N=1024)
            float* __restrict__ h_all){
  __shared__ __align__(16) uint4 wlds[8][WLDS][64];   // 136 KB weight tail
  __shared__ __align__(16) u16 hsh[2][4096];          // 16 KB double-buffered h
  const int bg = blockIdx.x, tid = threadIdx.x;
  const int w = tid >> 6, lane = tid & 63;
  const int am = lane & 15, oct = lane >> 4;
  const int hm = oct << 2, uc = am;
  const u32 abNos = (u32)(am * 512 + oct * 16);
  const u32 sw = (u32)((am & 7) << 4);
  ((uint4*)hsh[1])[tid] = make_uint4(0u, 0u, 0u, 0u);   // h(-1) = 0

  // resident weights: fid = P*32 + kc*4 + g ; nt = g*16 + w*2 + P
  uint4 wreg[WREG];
  #pragma unroll
  for (int fid = 0; fid < 64; fid++){
    const int P = fid >> 5, kc = (fid >> 2) & 7, g = fid & 3;
    const int nt = g * 16 + w * 2 + P;
    const uint4 v = bph[(size_t)((nt * 8 + kc) * 64) + lane];
    if (fid < WREG) wreg[fid] = v;
    else            wlds[w][fid - WREG][lane] = v;
  }

  const uint4* g0p = (const uint4*)g0l + ((size_t)((size_t)bg * NN * 8 + w) * 64 + lane) * 4;
  uint4 G0q[4];
  G0q[0] = g0p[0]; G0q[1] = g0p[1]; G0q[2] = g0p[2]; G0q[3] = g0p[3];
  g0p += 2048;

  const size_t hofs0 = ((size_t)(bg * 16 + hm) * NN) * 256 + (size_t)w * 32 + uc;
  float cst[8] = {0.f, 0.f, 0.f, 0.f, 0.f, 0.f, 0.f, 0.f};
  __syncthreads();

  #pragma unroll 1
  for (int n = 0; n < NN; n++){
    const char* hrd = (const char*)hsh[(n + 1) & 1];   // h(n-1)
    char* hwr = (char*)hsh[n & 1];                     // h(n)
    #pragma unroll
    for (int P = 0; P < 2; P++){
      f4_t acc[4] = {};
      #pragma unroll
      for (int kc = 0; kc < 8; kc++){
        FragU a;
        a.u = *(const uint4*)(hrd + ((abNos + (u32)(kc * 64)) ^ sw));
        #pragma unroll
        for (int g = 0; g < 4; g++){
          const int fid = P * 32 + kc * 4 + g;
          FragU b;
          if (fid < WREG) b.u = wreg[fid];
          else            b.u = wlds[w][fid - WREG][lane];
          acc[g] = mfma16(a, b, acc[g]);
        }
      }
      // gate math for ut = P: lane owns (m = hm+rr, u = w*32 + P*16 + uc)
      #pragma unroll
      for (int rr = 0; rr < 4; rr++){
        float gv[4];
        #pragma unroll
        for (int g = 0; g < 4; g++){
          const int t = P * 4 + g;
          const uint4 qv = G0q[t >> 1];
          const int wi = ((t & 1) << 1) + (rr >> 1);
          const u32 uw = (wi == 0) ? qv.x : (wi == 1) ? qv.y : (wi == 2) ? qv.z : qv.w;
          gv[g] = acc[g][rr] + ((rr & 1) ? hi16(uw) : lo16(uw));
        }
        const int ci = P * 4 + rr;
        const float cv = sigf(gv[1]) * cst[ci] + sigf(gv[0]) * tanh_(gv[2]);
        cst[ci] = cv;
        const float hv = sigf(gv[3]) * tanh_(cv);
        const int mm = hm + rr;
        const u32 wb = ((u32)(mm * 512 + (w * 32 + P * 16 + uc) * 2)) ^ ((u32)(mm & 7) << 4);
        *(u16*)(hwr + wb) = f2bf(hv);
        h_all[hofs0 + (size_t)rr * (NN * 256) + (size_t)n * 256 + P * 16] = hv;
      }
    }
    // issue next step's gate loads (consumed one full step later)
    if (n + 1 < NN){
      G0q[0] = g0p[0]; G0q[1] = g0p[1]; G0q[2] = g0p[2]; G0q[3] = g0p[3];
      g0p += 2048;
    }
    // publish h(n): drain LDS ops, barrier (no vmcnt drain), fence scheduling
    asm volatile("s_waitcnt lgkmcnt(0)" ::: "memory");
    __builtin_amdgcn_s_barrier();
    __builtin_amdgcn_sched_barrier(0);
  }
}

// ---------- final: y = sigmoid(concat(h, qn_emb, pn_emb) @ W_out + b_out) ; one wave per row
__global__ __launch_bounds__(256) void k_out(const float* __restrict__ h_all,
    const float* __restrict__ emb_q, const float* __restrict__ emb_p,
    const int* __restrict__ qn, const int* __restrict__ pn,
    const float* __restrict__ Wo, const float* __restrict__ bo, float* __restrict__ y){
  int m = blockIdx.x * 4 + (threadIdx.x >> 6);
  int lane = threadIdx.x & 63;
  const float* hr = h_all + (size_t)m * 256;
  const float* rq = emb_q + (size_t)qn[m] * 256;
  const float* rp = emb_p + (size_t)pn[m] * 256;
  float acc = 0.f;
  #pragma unroll
  for (int f = 0; f < 256; f += 64){
    int d = f + lane;
    acc += hr[d] * Wo[d];
    acc += rq[d] * Wo[256 + d];
    acc += rp[d] * Wo[512 + d];
  }
  acc = wred(acc);
  if (!lane) y[m] = sigf(acc + bo[0]);
}

// ---------- launch ----------
extern "C" void kernel_launch(void* const* d_in, const int* in_sizes, int n_in,
                              void* d_out, int out_size, void* d_ws, size_t ws_size,
                              hipStream_t stream){
  (void)n_in; (void)out_size; (void)ws_size;
  const int* p    = (const int*)d_in[1];
  const int* q    = (const int*)d_in[2];
  const int* r    = (const int*)d_in[3];
  const int* aff  = (const int*)d_in[4];
  const int* qn   = (const int*)d_in[5];
  const int* pn   = (const int*)d_in[6];
  const int* src  = (const int*)d_in[7];
  const int* dst  = (const int*)d_in[8];
  const float* emb_p  = (const float*)d_in[9];
  const float* emb_q  = (const float*)d_in[10];
  const float* emb_r  = (const float*)d_in[11];
  const float* emb_aff= (const float*)d_in[12];
  const float* W_aff  = (const float*)d_in[13];
  const float* b_aff  = (const float*)d_in[14];
  const float* W_g1   = (const float*)d_in[15];
  const float* a_s1   = (const float*)d_in[16];
  const float* a_d1   = (const float*)d_in[17];
  const float* b_g1   = (const float*)d_in[18];
  const float* W_g2   = (const float*)d_in[19];
  const float* a_s2   = (const float*)d_in[20];
  const float* a_d2   = (const float*)d_in[21];
  const float* b_g2   = (const float*)d_in[22];
  const float* W_ih   = (const float*)d_in[23];
  const float* W_hh   = (const float*)d_in[24];
  const float* b_ih   = (const float*)d_in[25];
  const float* b_hh   = (const float*)d_in[26];
  const float* W_out  = (const float*)d_in[27];
  const float* b_out  = (const float*)d_in[28];
  const int E = in_sizes[7];

  char* ws = (char*)d_ws;
  size_t off = 0;
  auto alloc = [&](size_t bytes){ size_t ret = off; off += (bytes + 255) & ~(size_t)255; return ret; };
  size_t o_bigA = alloc((size_t)MTOT * 1024 * 2);   // h1 bf16 -> gates bf16 (row layout)
  size_t o_bigB = alloc((size_t)MTOT * 1024 * 2);   // g1out bf16 -> x2 f32 -> G0L (lstm layout)
  size_t o_buf3 = alloc((size_t)MTOT * 256 * 4);    // x0 -> h2 -> h_all
  size_t o_es1 = alloc((size_t)MTOT * 8 * 4);
  size_t o_ed1 = alloc((size_t)MTOT * 8 * 4);
  size_t o_es2 = alloc((size_t)MTOT * 4);
  size_t o_ed2 = alloc((size_t)MTOT * 4);
  size_t o_whh = alloc((size_t)32768 * 16);      // W_hh^T B-frag pack (K=256,N=1024)
  size_t o_deg = alloc(512 * 4);
  size_t o_ins = alloc((size_t)NN * 4 * 4);
  size_t o_bpih  = alloc((size_t)131072 * 16);   // W_ih^T pack (K=1024,N=1024)
  size_t o_bpg1  = alloc((size_t)32768 * 16);    // W_g1 pack (K=256,N=1024)
  size_t o_bpg2  = alloc((size_t)32768 * 16);    // W_g2 pack (K=1024,N=256)
  size_t o_bpaff = alloc((size_t)16384 * 16);    // W_affcat pack (K=512,N=256)

  u16*   h1    = (u16*)(ws + o_bigA);
  u16*   gates = (u16*)(ws + o_bigA);
  u16*   g1out = (u16*)(ws + o_bigB);
  float* x2    = (float*)(ws + o_bigB);
  u16*   G0L   = (u16*)(ws + o_bigB);
  float* x0    = (float*)(ws + o_buf3);
  float* h2    = (float*)(ws + o_buf3);
  float* h_all = (float*)(ws + o_buf3);
  float* es1   = (float*)(ws + o_es1);
  float* ed1   = (float*)(ws + o_ed1);
  float* es2   = (float*)(ws + o_es2);
  float* ed2   = (float*)(ws + o_ed2);
  u16*   bphh  = (u16*)(ws + o_whh);
  int*   degp  = (int*)(ws + o_deg);
  int*   insp  = (int*)(ws + o_ins);
  u16*   bpih  = (u16*)(ws + o_bpih);
  u16*   bpg1  = (u16*)(ws + o_bpg1);
  u16*   bpg2  = (u16*)(ws + o_bpg2);
  u16*   bpaff = (u16*)(ws + o_bpaff);

  k_csr<<<1, 256, 0, stream>>>(src, dst, E, degp, insp);
  k_packB<<<128, 256, 0, stream>>>(W_hh, bphh, 256, 1024, 1);
  k_packB<<<512, 256, 0, stream>>>(W_ih, bpih, 1024, 1024, 1);
  k_packB<<<128, 256, 0, stream>>>(W_g1, bpg1, 256, 1024, 0);
  k_packB<<<128, 256, 0, stream>>>(W_g2, bpg2, 1024, 256, 0);
  k_packB<<<64, 256, 0, stream>>>(W_aff, bpaff, 512, 256, 0);

  k_affcat_m<<<dim3(NN, 2), 256, 0, stream>>>(emb_p, emb_aff, p, aff,
                                              (const uint4*)bpaff, b_aff, x0);
  k_h1_m<<<dim3(NN, 8), 256, 0, stream>>>(x0, (const uint4*)bpg1, h1);
  k_esed<<<(MTOT * 8) / 4, 256, 0, stream>>>(h1, nullptr, a_s1, a_d1, es1, ed1, 7, 128);
  k_gatagg<<<MTOT, 256, 0, stream>>>(h1, nullptr, es1, ed1, degp, insp, b_g1,
                                     g1out, nullptr, 8, 7, 1024, 1);
  k_h2_m<<<dim3(NN, 2), 256, 0, stream>>>(g1out, (const uint4*)bpg2, h2);
  k_esed<<<MTOT / 4, 256, 0, stream>>>(nullptr, h2, a_s2, a_d2, es2, ed2, 0, 256);
  k_gatagg<<<MTOT, 256, 0, stream>>>(nullptr, h2, es2, ed2, degp, insp, b_g2,
                                     nullptr, x2, 1, 8, 256, 0);
  k_gates_m<<<dim3(NN, 8), 256, 0, stream>>>(emb_p, emb_q, emb_r, p, q, r, x2,
                                             (const uint4*)bpih, b_ih, b_hh, gates);
  k_repack<<<dim3(NN, 8), 256, 0, stream>>>(gates, G0L);
  k_lstm<<<4, 512, 0, stream>>>(G0L, (const uint4*)bphh, h_all);
  k_out<<<MTOT / 4, 256, 0, stream>>>(h_all, emb_q, emb_p, qn, pn, W_out, b_out, (float*)d_out);
}

// Round 6
// 2794.695 us; speedup vs baseline: 2.2610x; 1.1149x over previous
//
#include <hip/hip_runtime.h>
#include <hip/hip_bf16.h>

typedef unsigned int u32;
typedef unsigned short u16;

#define MTOT 31936      // B*N = 64*499
#define NN 499
#define BB 64

// ---------- helpers ----------
__device__ __forceinline__ float lo16(u32 u){ return __uint_as_float(u << 16); }
__device__ __forceinline__ float hi16(u32 u){ return __uint_as_float(u & 0xffff0000u); }
__device__ __forceinline__ float bf2f(u16 u){ return __uint_as_float(((u32)u) << 16); }
__device__ __forceinline__ u16 f2bf(float f){
  u32 x = __float_as_uint(f);
  u32 r = (x + 0x7fffu + ((x >> 16) & 1u)) >> 16;   // RNE
  return (u16)r;
}
__device__ __forceinline__ float sigf(float x){ return 1.f / (1.f + __expf(-x)); }
__device__ __forceinline__ float tanh_(float x){ return 2.f * sigf(2.f * x) - 1.f; }
__device__ __forceinline__ float wred(float v){
  #pragma unroll
  for (int off = 32; off; off >>= 1) v += __shfl_down(v, off, 64);
  return v;
}

typedef __attribute__((ext_vector_type(2))) __bf16 bf16x2;

// pack two f32 -> u32 of two bf16 (RNE)
#if __has_builtin(__builtin_amdgcn_cvt_pk_bf16_f32)
__device__ __forceinline__ u32 pk2bf(float a, float b){
  union { bf16x2 v; u32 u; } r;
  r.v = __builtin_amdgcn_cvt_pk_bf16_f32(a, b);
  return r.u;
}
#else
__device__ __forceinline__ u32 pk2bf(float a, float b){
  return (u32)f2bf(a) | ((u32)f2bf(b) << 16);
}
#endif

// ---------- MFMA plumbing (16x16x32 bf16) ----------
// A-frag: lane holds A[m=lane&15][k=(lane>>4)*8 + j], j=0..7  (8 bf16 = uint4)
// B-frag: lane holds B[k=(lane>>4)*8 + j][n=lane&15]
// C/D   : reg r at row=(lane>>4)*4+r, col=lane&15
typedef __attribute__((ext_vector_type(8))) short bfrag8;
typedef __attribute__((ext_vector_type(4))) float f4_t;
union FragU { uint4 u; bfrag8 s; };

__device__ __forceinline__ f4_t mfma16(FragU a, FragU b, f4_t c){
  return __builtin_amdgcn_mfma_f32_16x16x32_bf16(a.s, b.s, c, 0, 0, 0);
}

// GEMM core v2: 64M x 128N tile, 4 waves; ntBase selects this wave's 2 N-tiles.
// A (64Mx32K per kt) staged in LDS (double-buffered, one barrier/kt); B frags from global.
template <typename AL>
__device__ __forceinline__ void gemm_core2(int K32, const uint4* __restrict__ Bpack,
                                           int ntBase, f4_t (&acc)[4][2], AL aload){
  __shared__ __align__(16) uint4 As[2][256];
  const int tid = threadIdx.x;
  const int lane = tid & 63;
  const uint4* Bp0 = Bpack + ((size_t)ntBase * K32) * 64 + lane;
  const uint4* Bp1 = Bp0 + (size_t)K32 * 64;
  int buf = 0;
  for (int kt = 0; kt < K32; kt++){
    FragU b0, b1;
    b0.u = Bp0[kt * 64];
    b1.u = Bp1[kt * 64];
    As[buf][tid] = aload(kt);
    __syncthreads();
    FragU a0, a1, a2, a3;
    a0.u = As[buf][lane];
    a1.u = As[buf][64 + lane];
    a2.u = As[buf][128 + lane];
    a3.u = As[buf][192 + lane];
    acc[0][0] = mfma16(a0, b0, acc[0][0]); acc[0][1] = mfma16(a0, b1, acc[0][1]);
    acc[1][0] = mfma16(a1, b0, acc[1][0]); acc[1][1] = mfma16(a1, b1, acc[1][1]);
    acc[2][0] = mfma16(a2, b0, acc[2][0]); acc[2][1] = mfma16(a2, b1, acc[2][1]);
    acc[3][0] = mfma16(a3, b0, acc[3][0]); acc[3][1] = mfma16(a3, b1, acc[3][1]);
    buf ^= 1;
  }
}

// ---------- prep: pack weight matrix into B-fragment-layout bf16 chunks ----------
// chunk c: nt=c/(K32*64), kt=(c/64)%K32, l=c&63 -> holds B[k=kt*32+(l>>4)*8+j][n=nt*16+(l&15)]
// trans=0: B[k][n] = W[k*N+n] ; trans=1: B[k][n] = W[n*K+k]
__global__ __launch_bounds__(256) void k_packB(const float* __restrict__ W, u16* __restrict__ out,
                                               int K, int N, int trans){
  int c = blockIdx.x * 256 + threadIdx.x;
  int K32 = K >> 5;
  int total = (N >> 4) * K32 * 64;
  if (c >= total) return;
  int l = c & 63;
  int rem = c >> 6;
  int kt = rem % K32, nt = rem / K32;
  int n = nt * 16 + (l & 15);
  int kb = kt * 32 + (l >> 4) * 8;
  u32 ov[4];
  #pragma unroll
  for (int j2 = 0; j2 < 4; j2++){
    int k = kb + j2 * 2;
    float f0 = trans ? W[(size_t)n * K + k]     : W[(size_t)k * N + n];
    float f1 = trans ? W[(size_t)n * K + k + 1] : W[(size_t)(k + 1) * N + n];
    ov[j2] = pk2bf(f0, f1);
  }
  uint4 o; o.x = ov[0]; o.y = ov[1]; o.z = ov[2]; o.w = ov[3];
  *(uint4*)(out + (size_t)c * 8) = o;
}

// ---------- CSR build (chain graph, in-degree <= 3) ----------
__global__ void k_csr(const int* __restrict__ src, const int* __restrict__ dst, int E,
                      int* __restrict__ deg, int* __restrict__ insrc){
  int tid = threadIdx.x;
  for (int i = tid; i < NN; i += 256) deg[i] = 0;
  for (int i = tid; i < NN * 4; i += 256) insrc[i] = 0;
  __syncthreads();
  for (int e = tid; e < E; e += 256){
    int d = dst[e];
    int slot = atomicAdd(&deg[d], 1);
    if (slot < 4) insrc[d * 4 + slot] = src[e];
  }
}

// ---------- GEMM 1 (MFMA): x0 = concat(emb_p[p], emb_aff[aff]) @ W_affcat + b ; K=512, N=256, f32 out
__global__ __launch_bounds__(256) void k_affcat_m(
    const float* __restrict__ emb_p, const float* __restrict__ emb_aff,
    const int* __restrict__ p, const int* __restrict__ aff,
    const uint4* __restrict__ Bpack, const float* __restrict__ bias, float* __restrict__ C){
  const int tid = threadIdx.x;
  const int mBase = blockIdx.x * 64, nBase = blockIdx.y * 128;
  const int ls = tid & 63;
  const int gm = mBase + (tid >> 6) * 16 + (ls & 15);
  const int kqoff = (ls >> 4) * 8;
  const float* rp = emb_p + (size_t)p[gm] * 256 + kqoff;
  const float* ra = emb_aff + (size_t)aff[gm] * 256 + kqoff;
  f4_t acc[4][2] = {};
  gemm_core2(16, Bpack, blockIdx.y * 8 + ((tid >> 6) << 1), acc, [&](int kt) -> uint4 {
    int kb = kt * 32;
    const float* s = (kb < 256) ? (rp + kb) : (ra + kb - 256);
    float4 v0 = *(const float4*)s;
    float4 v1 = *(const float4*)(s + 4);
    uint4 o; o.x = pk2bf(v0.x, v0.y); o.y = pk2bf(v0.z, v0.w);
    o.z = pk2bf(v1.x, v1.y); o.w = pk2bf(v1.z, v1.w);
    return o;
  });
  const int wave = tid >> 6, lane = tid & 63;
  const int rb = (lane >> 4) << 2;
  const int cbase = nBase + wave * 32 + (lane & 15);
  float b0 = bias[cbase], b1 = bias[cbase + 16];
  #pragma unroll
  for (int i = 0; i < 4; i++)
    #pragma unroll
    for (int r = 0; r < 4; r++){
      int row = mBase + i * 16 + rb + r;
      C[(size_t)row * 256 + cbase]      = acc[i][0][r] + b0;
      C[(size_t)row * 256 + cbase + 16] = acc[i][1][r] + b1;
    }
}

// ---------- GEMM 2 (MFMA): h1 = x0 @ W_g1 ; K=256, N=1024, bf16 out
__global__ __launch_bounds__(256) void k_h1_m(const float* __restrict__ A,
                                              const uint4* __restrict__ Bpack,
                                              u16* __restrict__ Cb){
  const int tid = threadIdx.x;
  const int mBase = blockIdx.x * 64, nBase = blockIdx.y * 128;
  const int ls = tid & 63;
  const int gm = mBase + (tid >> 6) * 16 + (ls & 15);
  const float* ra = A + (size_t)gm * 256 + (ls >> 4) * 8;
  f4_t acc[4][2] = {};
  gemm_core2(8, Bpack, blockIdx.y * 8 + ((tid >> 6) << 1), acc, [&](int kt) -> uint4 {
    const float* s = ra + kt * 32;
    float4 v0 = *(const float4*)s;
    float4 v1 = *(const float4*)(s + 4);
    uint4 o; o.x = pk2bf(v0.x, v0.y); o.y = pk2bf(v0.z, v0.w);
    o.z = pk2bf(v1.x, v1.y); o.w = pk2bf(v1.z, v1.w);
    return o;
  });
  const int wave = tid >> 6, lane = tid & 63;
  const int rb = (lane >> 4) << 2;
  const int cbase = nBase + wave * 32 + (lane & 15);
  #pragma unroll
  for (int i = 0; i < 4; i++)
    #pragma unroll
    for (int r = 0; r < 4; r++){
      int row = mBase + i * 16 + rb + r;
      Cb[(size_t)row * 1024 + cbase]      = f2bf(acc[i][0][r]);
      Cb[(size_t)row * 1024 + cbase + 16] = f2bf(acc[i][1][r]);
    }
}

// ---------- GEMM 3 (MFMA): h2 = g1out @ W_g2 ; K=1024, N=256, f32 out ; A already bf16
__global__ __launch_bounds__(256) void k_h2_m(const u16* __restrict__ A,
                                              const uint4* __restrict__ Bpack,
                                              float* __restrict__ C){
  const int tid = threadIdx.x;
  const int mBase = blockIdx.x * 64, nBase = blockIdx.y * 128;
  const int ls = tid & 63;
  const int gm = mBase + (tid >> 6) * 16 + (ls & 15);
  const u16* ra = A + (size_t)gm * 1024 + (ls >> 4) * 8;
  f4_t acc[4][2] = {};
  gemm_core2(32, Bpack, blockIdx.y * 8 + ((tid >> 6) << 1), acc, [&](int kt) -> uint4 {
    return *(const uint4*)(ra + kt * 32);
  });
  const int wave = tid >> 6, lane = tid & 63;
  const int rb = (lane >> 4) << 2;
  const int cbase = nBase + wave * 32 + (lane & 15);
  #pragma unroll
  for (int i = 0; i < 4; i++)
    #pragma unroll
    for (int r = 0; r < 4; r++){
      int row = mBase + i * 16 + rb + r;
      C[(size_t)row * 256 + cbase]      = acc[i][0][r];
      C[(size_t)row * 256 + cbase + 16] = acc[i][1][r];
    }
}

// ---------- GEMM 4 (MFMA): gates = concat(p,q,r,x2) @ W_ih^T + bih + bhh ; K=1024, N=1024, bf16 out
// (round-0-proven structure; standard [row][1024] output layout)
__global__ __launch_bounds__(256) void k_gates_m(
    const float* __restrict__ emb_p, const float* __restrict__ emb_q, const float* __restrict__ emb_r,
    const int* __restrict__ p, const int* __restrict__ q, const int* __restrict__ r,
    const float* __restrict__ x2, const uint4* __restrict__ Bpack,
    const float* __restrict__ bih, const float* __restrict__ bhh, u16* __restrict__ Cb){
  const int tid = threadIdx.x;
  const int mBase = blockIdx.x * 64, nBase = blockIdx.y * 128;
  const int ls = tid & 63;
  const int gm = mBase + (tid >> 6) * 16 + (ls & 15);
  const int kqoff = (ls >> 4) * 8;
  const float* s0 = emb_p + (size_t)p[gm] * 256 + kqoff;
  const float* s1 = emb_q + (size_t)q[gm] * 256 + kqoff;
  const float* s2 = emb_r + (size_t)r[gm] * 256 + kqoff;
  const float* s3 = x2 + (size_t)gm * 256 + kqoff;
  f4_t acc[4][2] = {};
  gemm_core2(32, Bpack, blockIdx.y * 8 + ((tid >> 6) << 1), acc, [&](int kt) -> uint4 {
    int kb = kt * 32;
    int seg = kb >> 8, ko = kb & 255;
    const float* s = (seg == 0) ? s0 : ((seg == 1) ? s1 : ((seg == 2) ? s2 : s3));
    float4 v0 = *(const float4*)(s + ko);
    float4 v1 = *(const float4*)(s + ko + 4);
    uint4 o; o.x = pk2bf(v0.x, v0.y); o.y = pk2bf(v0.z, v0.w);
    o.z = pk2bf(v1.x, v1.y); o.w = pk2bf(v1.z, v1.w);
    return o;
  });
  const int wave = tid >> 6, lane = tid & 63;
  const int rb = (lane >> 4) << 2;
  const int cbase = nBase + wave * 32 + (lane & 15);
  float b0 = bih[cbase] + bhh[cbase];
  float b1 = bih[cbase + 16] + bhh[cbase + 16];
  #pragma unroll
  for (int i = 0; i < 4; i++)
    #pragma unroll
    for (int r2 = 0; r2 < 4; r2++){
      int row = mBase + i * 16 + rb + r2;
      Cb[(size_t)row * 1024 + cbase]      = f2bf(acc[i][0][r2] + b0);
      Cb[(size_t)row * 1024 + cbase + 16] = f2bf(acc[i][1][r2] + b1);
    }
}

// ---------- repack gates [row=b*NN+n][1024] -> LSTM stream layout ----------
// out u16 idx: ((((bg*NN+n)*8 + w)*64 + L)*32 + t*4 + rt)
//   value = gates[(bg*16 + ((L>>4)<<2) + rt)*NN + n][g*256 + w*32 + ut*16 + (L&15)]
//   with g = t&3, ut = t>>2. Block = (n, w); LDS-staged; coalesced 16B in/out.
__global__ __launch_bounds__(256) void k_repack(const u16* __restrict__ gates,
                                                u16* __restrict__ G0L){
  __shared__ __align__(16) u16 staged[64][128];
  const int tid = threadIdx.x;
  const int n = blockIdx.x, w = blockIdx.y;
  #pragma unroll
  for (int i = 0; i < 4; i++){
    const int c = tid + i * 256;           // 1024 chunks of 8 u16
    const int b = c >> 4, seg = c & 15;    // staged[b][seg*8 .. +8)
    const int t = seg >> 1, cc8 = (seg & 1) * 8;
    const int g = t & 3, ut = t >> 2;
    const u16* srcp = gates + (size_t)(b * NN + n) * 1024 + g * 256 + w * 32 + ut * 16 + cc8;
    *(uint4*)&staged[b][seg * 8] = *(const uint4*)srcp;
  }
  __syncthreads();
  const int Lt = tid >> 2, qq = tid & 3;
  const int mhi = (Lt >> 4) << 2;
  const int cc = Lt & 15;
  #pragma unroll
  for (int bg = 0; bg < 4; bg++){
    u32 vw[4];
    #pragma unroll
    for (int j = 0; j < 4; j++){
      const int t = 2 * qq + (j >> 1);
      const int r0 = (2 * j) & 3;          // 0,2,0,2
      const u16 lo = staged[bg * 16 + mhi + r0][t * 16 + cc];
      const u16 hi = staged[bg * 16 + mhi + r0 + 1][t * 16 + cc];
      vw[j] = (u32)lo | ((u32)hi << 16);
    }
    uint4 o; o.x = vw[0]; o.y = vw[1]; o.z = vw[2]; o.w = vw[3];
    *(uint4*)(G0L + ((((size_t)(bg * NN + n) * 8 + w) * 64 + Lt) * 32 + qq * 8)) = o;
  }
}

// ---------- es/ed: per (m,h) dots of h-row with a_src / a_dst ; one wave per w = m*H+h
__global__ __launch_bounds__(256) void k_esed(
    const u16* __restrict__ hb, const float* __restrict__ hf,
    const float* __restrict__ asrc, const float* __restrict__ adst,
    float* __restrict__ es, float* __restrict__ ed, int Hm1, int Fo){
  int w = blockIdx.x * 4 + (threadIdx.x >> 6);
  int lane = threadIdx.x & 63;
  int h = w & Hm1;
  size_t base = (size_t)w * Fo;
  float s = 0.f, d = 0.f;
  for (int f = lane; f < Fo; f += 64){
    float hv = hb ? bf2f(hb[base + f]) : hf[base + f];
    s += hv * asrc[h * Fo + f];
    d += hv * adst[h * Fo + f];
  }
  s = wred(s); d = wred(d);
  if (!lane){ es[w] = s; ed[w] = d; }
}

// ---------- GAT aggregation: segment softmax (deg<=3) + weighted sum + bias (+ELU)
__global__ __launch_bounds__(256) void k_gatagg(
    const u16* __restrict__ hb, const float* __restrict__ hf,
    const float* __restrict__ es, const float* __restrict__ ed,
    const int* __restrict__ deg, const int* __restrict__ insrc,
    const float* __restrict__ bias, u16* __restrict__ outb, float* __restrict__ outf,
    int H, int foShift, int HFo, int do_elu){
  int m = blockIdx.x;
  int b = m / NN;
  int n = m - b * NN;
  int dg = deg[n];
  int s0 = insrc[n * 4 + 0];
  int s1 = insrc[n * 4 + 1];
  int s2 = insrc[n * 4 + 2];
  int rowBase = b * NN;
  for (int c = threadIdx.x; c < HFo; c += 256){
    int h = c >> foShift;
    float edv = ed[(size_t)m * H + h];
    float sc0 = es[(size_t)(rowBase + s0) * H + h] + edv;
    sc0 = (sc0 >= 0.f) ? sc0 : 0.2f * sc0;
    float sc1 = 0.f, sc2 = 0.f, mx = sc0;
    if (dg > 1){ sc1 = es[(size_t)(rowBase + s1) * H + h] + edv; sc1 = (sc1 >= 0.f) ? sc1 : 0.2f * sc1; mx = fmaxf(mx, sc1); }
    if (dg > 2){ sc2 = es[(size_t)(rowBase + s2) * H + h] + edv; sc2 = (sc2 >= 0.f) ? sc2 : 0.2f * sc2; mx = fmaxf(mx, sc2); }
    float e0 = __expf(sc0 - mx), e1 = 0.f, e2 = 0.f;
    if (dg > 1) e1 = __expf(sc1 - mx);
    if (dg > 2) e2 = __expf(sc2 - mx);
    float inv = 1.f / (e0 + e1 + e2);
    size_t c0 = (size_t)(rowBase + s0) * HFo + c;
    float acc = e0 * (hb ? bf2f(hb[c0]) : hf[c0]);
    if (dg > 1){ size_t c1 = (size_t)(rowBase + s1) * HFo + c; acc += e1 * (hb ? bf2f(hb[c1]) : hf[c1]); }
    if (dg > 2){ size_t c2 = (size_t)(rowBase + s2) * HFo + c; acc += e2 * (hb ? bf2f(hb[c2]) : hf[c2]); }
    acc *= inv;
    float o = acc + bias[c];
    if (do_elu) o = (o > 0.f) ? o : (__expf(o) - 1.f);
    if (outb) outb[(size_t)m * HFo + c] = f2bf(o);
    else      outf[(size_t)m * HFo + c] = o;
  }
}

// ---------- LSTM recurrence v16 (MFMA, resident+streamed weights, no spill) ----------
// Round-5 post-mortem: v15's WREG=47 (188 regs) exceeded the 128-AGPR half of the
// unified file; pass-1's 15 reg-frags spilled to scratch and were refilled with
// ZERO issue lead (~350cy serialized each) -> 4.77us/step. v16 sizes each tier to
// what actually fits and streams the overflow EXPLICITLY with long issue lead:
//   REG  (32 frags = 128 regs, = AGPR capacity): pass0 g0..g2 (24), pass0 g3 kc0,
//        pass1 g2 kc1..7.
//   LDS  (17 frags, 136KB, same footprint as passing v15): pass1 g0, g1, g2-kc0.
//   STREAM (15 frags, all g3): one per k-phase, 6-deep register ring (24 regs in
//        flight), each load issued ~6 phases (>=250cy) before use; next step's
//        prologue issued before this step's second gate-math (~800cy lead).
// Frag(P,g,kc) lives at bph[((g*16 + w*2 + P)*8 + kc)*64 + lane].
// Everything else (layout, gate math, barrier) identical to v15 (ran + passed).
#define WREG 32
#define WLDS 17
__global__ __launch_bounds__(512)
__attribute__((amdgpu_waves_per_eu(2, 2)))
void k_lstm(const u16* __restrict__ g0l,      // gates in k_repack layout
            const uint4* __restrict__ bph,    // packed W_hh^T B-frags (K=256,N=1024)
            float* __restrict__ h_all){
  __shared__ __align__(16) uint4 wlds[8][WLDS][64];   // 136 KB weight tail
  __shared__ __align__(16) u16 hsh[2][4096];          // 16 KB double-buffered h
  const int bg = blockIdx.x, tid = threadIdx.x;
  const int w = tid >> 6, lane = tid & 63;
  const int am = lane & 15, oct = lane >> 4;
  const int hm = oct << 2, uc = am;
  const u32 abNos = (u32)(am * 512 + oct * 16);
  const u32 sw = (u32)((am & 7) << 4);
  ((uint4*)hsh[1])[tid] = make_uint4(0u, 0u, 0u, 0u);   // h(-1) = 0

  // ---- resident weights ----
  uint4 wreg[WREG];
  #pragma unroll
  for (int kc = 0; kc < 8; kc++)
    #pragma unroll
    for (int g = 0; g < 3; g++)     // pass0 g0..g2
      wreg[kc * 3 + g] = bph[(size_t)(((g * 16 + w * 2) * 8 + kc) * 64) + lane];
  wreg[24] = bph[(size_t)(((48 + w * 2) * 8) * 64) + lane];   // pass0 g3 kc0
  #pragma unroll
  for (int kc = 1; kc < 8; kc++)    // pass1 g2 kc1..7
    wreg[24 + kc] = bph[(size_t)(((32 + w * 2 + 1) * 8 + kc) * 64) + lane];
  #pragma unroll
  for (int kc = 0; kc < 8; kc++){
    wlds[w][kc][lane]     = bph[(size_t)(((w * 2 + 1) * 8 + kc) * 64) + lane];        // pass1 g0
    wlds[w][8 + kc][lane] = bph[(size_t)(((16 + w * 2 + 1) * 8 + kc) * 64) + lane];   // pass1 g1
  }
  wlds[w][16][lane] = bph[(size_t)(((32 + w * 2 + 1) * 8) * 64) + lane];              // pass1 g2 kc0

  // ---- stream base: frag(P, g3, kc) = sp[(P*8 + kc)*64]; sid s <-> offset (s+1)*64
  const uint4* sp = bph + (size_t)(((48 + w * 2) * 8) * 64) + lane;

  const uint4* g0p = (const uint4*)g0l + ((size_t)((size_t)bg * NN * 8 + w) * 64 + lane) * 4;
  uint4 G0q[4];
  G0q[0] = g0p[0]; G0q[1] = g0p[1]; G0q[2] = g0p[2]; G0q[3] = g0p[3];
  g0p += 2048;

  const size_t hofs0 = ((size_t)(bg * 16 + hm) * NN) * 256 + (size_t)w * 32 + uc;
  float cst[8] = {0.f, 0.f, 0.f, 0.f, 0.f, 0.f, 0.f, 0.f};

  // ring prologue for step 0: sids 0..5
  uint4 wstr[6];
  #pragma unroll
  for (int s = 0; s < 6; s++) wstr[s] = sp[(s + 1) * 64];
  __syncthreads();

  #pragma unroll 1
  for (int n = 0; n < NN; n++){
    const char* hrd = (const char*)hsh[(n + 1) & 1];   // h(n-1)
    char* hwr = (char*)hsh[n & 1];                     // h(n)
    #pragma unroll
    for (int P = 0; P < 2; P++){
      f4_t acc[4] = {};
      #pragma unroll
      for (int kc = 0; kc < 8; kc++){
        const int ph = P * 8 + kc;          // 0..15, compile-time
        FragU a;
        a.u = *(const uint4*)(hrd + ((abNos + (u32)(kc * 64)) ^ sw));
        #pragma unroll
        for (int g = 0; g < 4; g++){
          FragU b;
          if (P == 0){
            if (g < 3)            b.u = wreg[kc * 3 + g];
            else if (kc == 0)     b.u = wreg[24];
            else                  b.u = wstr[(ph - 1) % 6];
          } else {
            if (g == 0)           b.u = wlds[w][kc][lane];
            else if (g == 1)      b.u = wlds[w][8 + kc][lane];
            else if (g == 2)      b.u = (kc == 0) ? wlds[w][16][lane] : wreg[24 + kc];
            else                  b.u = wstr[(ph - 1) % 6];
          }
          acc[g] = mfma16(a, b, acc[g]);
        }
        // ring reissue: sid ph+5 into the slot just consumed (sid ph-1), 6-phase lead
        if (ph >= 1 && ph <= 9)
          wstr[(ph + 5) % 6] = sp[(ph + 6) * 64];
      }
      // after pass1's consumes: issue NEXT step's prologue (sids 0..5) so the
      // first consumes of step n+1 have gate-math + barrier worth of lead
      if (P == 1){
        #pragma unroll
        for (int s = 0; s < 6; s++) wstr[s] = sp[(s + 1) * 64];
      }
      // gate math for ut = P: lane owns (m = hm+rr, u = w*32 + P*16 + uc)
      #pragma unroll
      for (int rr = 0; rr < 4; rr++){
        float gv[4];
        #pragma unroll
        for (int g = 0; g < 4; g++){
          const int t = P * 4 + g;
          const uint4 qv = G0q[t >> 1];
          const int wi = ((t & 1) << 1) + (rr >> 1);
          const u32 uw = (wi == 0) ? qv.x : (wi == 1) ? qv.y : (wi == 2) ? qv.z : qv.w;
          gv[g] = acc[g][rr] + ((rr & 1) ? hi16(uw) : lo16(uw));
        }
        const int ci = P * 4 + rr;
        const float cv = sigf(gv[1]) * cst[ci] + sigf(gv[0]) * tanh_(gv[2]);
        cst[ci] = cv;
        const float hv = sigf(gv[3]) * tanh_(cv);
        const int mm = hm + rr;
        const u32 wb = ((u32)(mm * 512 + (w * 32 + P * 16 + uc) * 2)) ^ ((u32)(mm & 7) << 4);
        *(u16*)(hwr + wb) = f2bf(hv);
        h_all[hofs0 + (size_t)rr * (NN * 256) + (size_t)n * 256 + P * 16] = hv;
      }
    }
    // issue next step's gate loads (consumed one full step later)
    if (n + 1 < NN){
      G0q[0] = g0p[0]; G0q[1] = g0p[1]; G0q[2] = g0p[2]; G0q[3] = g0p[3];
      g0p += 2048;
    }
    // publish h(n): drain LDS ops, barrier (no vmcnt drain), fence scheduling
    asm volatile("s_waitcnt lgkmcnt(0)" ::: "memory");
    __builtin_amdgcn_s_barrier();
    __builtin_amdgcn_sched_barrier(0);
  }
}

// ---------- final: y = sigmoid(concat(h, qn_emb, pn_emb) @ W_out + b_out) ; one wave per row
__global__ __launch_bounds__(256) void k_out(const float* __restrict__ h_all,
    const float* __restrict__ emb_q, const float* __restrict__ emb_p,
    const int* __restrict__ qn, const int* __restrict__ pn,
    const float* __restrict__ Wo, const float* __restrict__ bo, float* __restrict__ y){
  int m = blockIdx.x * 4 + (threadIdx.x >> 6);
  int lane = threadIdx.x & 63;
  const float* hr = h_all + (size_t)m * 256;
  const float* rq = emb_q + (size_t)qn[m] * 256;
  const float* rp = emb_p + (size_t)pn[m] * 256;
  float acc = 0.f;
  #pragma unroll
  for (int f = 0; f < 256; f += 64){
    int d = f + lane;
    acc += hr[d] * Wo[d];
    acc += rq[d] * Wo[256 + d];
    acc += rp[d] * Wo[512 + d];
  }
  acc = wred(acc);
  if (!lane) y[m] = sigf(acc + bo[0]);
}

// ---------- launch ----------
extern "C" void kernel_launch(void* const* d_in, const int* in_sizes, int n_in,
                              void* d_out, int out_size, void* d_ws, size_t ws_size,
                              hipStream_t stream){
  (void)n_in; (void)out_size; (void)ws_size;
  const int* p    = (const int*)d_in[1];
  const int* q    = (const int*)d_in[2];
  const int* r    = (const int*)d_in[3];
  const int* aff  = (const int*)d_in[4];
  const int* qn   = (const int*)d_in[5];
  const int* pn   = (const int*)d_in[6];
  const int* src  = (const int*)d_in[7];
  const int* dst  = (const int*)d_in[8];
  const float* emb_p  = (const float*)d_in[9];
  const float* emb_q  = (const float*)d_in[10];
  const float* emb_r  = (const float*)d_in[11];
  const float* emb_aff= (const float*)d_in[12];
  const float* W_aff  = (const float*)d_in[13];
  const float* b_aff  = (const float*)d_in[14];
  const float* W_g1   = (const float*)d_in[15];
  const float* a_s1   = (const float*)d_in[16];
  const float* a_d1   = (const float*)d_in[17];
  const float* b_g1   = (const float*)d_in[18];
  const float* W_g2   = (const float*)d_in[19];
  const float* a_s2   = (const float*)d_in[20];
  const float* a_d2   = (const float*)d_in[21];
  const float* b_g2   = (const float*)d_in[22];
  const float* W_ih   = (const float*)d_in[23];
  const float* W_hh   = (const float*)d_in[24];
  const float* b_ih   = (const float*)d_in[25];
  const float* b_hh   = (const float*)d_in[26];
  const float* W_out  = (const float*)d_in[27];
  const float* b_out  = (const float*)d_in[28];
  const int E = in_sizes[7];

  char* ws = (char*)d_ws;
  size_t off = 0;
  auto alloc = [&](size_t bytes){ size_t ret = off; off += (bytes + 255) & ~(size_t)255; return ret; };
  size_t o_bigA = alloc((size_t)MTOT * 1024 * 2);   // h1 bf16 -> gates bf16 (row layout)
  size_t o_bigB = alloc((size_t)MTOT * 1024 * 2);   // g1out bf16 -> x2 f32 -> G0L (lstm layout)
  size_t o_buf3 = alloc((size_t)MTOT * 256 * 4);    // x0 -> h2 -> h_all
  size_t o_es1 = alloc((size_t)MTOT * 8 * 4);
  size_t o_ed1 = alloc((size_t)MTOT * 8 * 4);
  size_t o_es2 = alloc((size_t)MTOT * 4);
  size_t o_ed2 = alloc((size_t)MTOT * 4);
  size_t o_whh = alloc((size_t)32768 * 16);      // W_hh^T B-frag pack (K=256,N=1024)
  size_t o_deg = alloc(512 * 4);
  size_t o_ins = alloc((size_t)NN * 4 * 4);
  size_t o_bpih  = alloc((size_t)131072 * 16);   // W_ih^T pack (K=1024,N=1024)
  size_t o_bpg1  = alloc((size_t)32768 * 16);    // W_g1 pack (K=256,N=1024)
  size_t o_bpg2  = alloc((size_t)32768 * 16);    // W_g2 pack (K=1024,N=256)
  size_t o_bpaff = alloc((size_t)16384 * 16);    // W_affcat pack (K=512,N=256)

  u16*   h1    = (u16*)(ws + o_bigA);
  u16*   gates = (u16*)(ws + o_bigA);
  u16*   g1out = (u16*)(ws + o_bigB);
  float* x2    = (float*)(ws + o_bigB);
  u16*   G0L   = (u16*)(ws + o_bigB);
  float* x0    = (float*)(ws + o_buf3);
  float* h2    = (float*)(ws + o_buf3);
  float* h_all = (float*)(ws + o_buf3);
  float* es1   = (float*)(ws + o_es1);
  float* ed1   = (float*)(ws + o_ed1);
  float* es2   = (float*)(ws + o_es2);
  float* ed2   = (float*)(ws + o_ed2);
  u16*   bphh  = (u16*)(ws + o_whh);
  int*   degp  = (int*)(ws + o_deg);
  int*   insp  = (int*)(ws + o_ins);
  u16*   bpih  = (u16*)(ws + o_bpih);
  u16*   bpg1  = (u16*)(ws + o_bpg1);
  u16*   bpg2  = (u16*)(ws + o_bpg2);
  u16*   bpaff = (u16*)(ws + o_bpaff);

  k_csr<<<1, 256, 0, stream>>>(src, dst, E, degp, insp);
  k_packB<<<128, 256, 0, stream>>>(W_hh, bphh, 256, 1024, 1);
  k_packB<<<512, 256, 0, stream>>>(W_ih, bpih, 1024, 1024, 1);
  k_packB<<<128, 256, 0, stream>>>(W_g1, bpg1, 256, 1024, 0);
  k_packB<<<128, 256, 0, stream>>>(W_g2, bpg2, 1024, 256, 0);
  k_packB<<<64, 256, 0, stream>>>(W_aff, bpaff, 512, 256, 0);

  k_affcat_m<<<dim3(NN, 2), 256, 0, stream>>>(emb_p, emb_aff, p, aff,
                                              (const uint4*)bpaff, b_aff, x0);
  k_h1_m<<<dim3(NN, 8), 256, 0, stream>>>(x0, (const uint4*)bpg1, h1);
  k_esed<<<(MTOT * 8) / 4, 256, 0, stream>>>(h1, nullptr, a_s1, a_d1, es1, ed1, 7, 128);
  k_gatagg<<<MTOT, 256, 0, stream>>>(h1, nullptr, es1, ed1, degp, insp, b_g1,
                                     g1out, nullptr, 8, 7, 1024, 1);
  k_h2_m<<<dim3(NN, 2), 256, 0, stream>>>(g1out, (const uint4*)bpg2, h2);
  k_esed<<<MTOT / 4, 256, 0, stream>>>(nullptr, h2, a_s2, a_d2, es2, ed2, 0, 256);
  k_gatagg<<<MTOT, 256, 0, stream>>>(nullptr, h2, es2, ed2, degp, insp, b_g2,
                                     nullptr, x2, 1, 8, 256, 0);
  k_gates_m<<<dim3(NN, 8), 256, 0, stream>>>(emb_p, emb_q, emb_r, p, q, r, x2,
                                             (const uint4*)bpih, b_ih, b_hh, gates);
  k_repack<<<dim3(NN, 8), 256, 0, stream>>>(gates, G0L);
  k_lstm<<<4, 512, 0, stream>>>(G0L, (const uint4*)bphh, h_all);
  k_out<<<MTOT / 4, 256, 0, stream>>>(h_all, emb_q, emb_p, qn, pn, W_out, b_out, (float*)d_out);
}

// Round 7
// 1529.276 us; speedup vs baseline: 4.1319x; 1.8275x over previous
//
#include <hip/hip_runtime.h>
#include <hip/hip_bf16.h>

typedef unsigned int u32;
typedef unsigned short u16;

#define MTOT 31936      // B*N = 64*499
#define NN 499
#define BB 64

// ---------- helpers ----------
__device__ __forceinline__ float lo16(u32 u){ return __uint_as_float(u << 16); }
__device__ __forceinline__ float hi16(u32 u){ return __uint_as_float(u & 0xffff0000u); }
__device__ __forceinline__ float bf2f(u16 u){ return __uint_as_float(((u32)u) << 16); }
__device__ __forceinline__ u16 f2bf(float f){
  u32 x = __float_as_uint(f);
  u32 r = (x + 0x7fffu + ((x >> 16) & 1u)) >> 16;   // RNE
  return (u16)r;
}
__device__ __forceinline__ float sigf(float x){ return 1.f / (1.f + __expf(-x)); }
__device__ __forceinline__ float tanh_(float x){ return 2.f * sigf(2.f * x) - 1.f; }
__device__ __forceinline__ float wred(float v){
  #pragma unroll
  for (int off = 32; off; off >>= 1) v += __shfl_down(v, off, 64);
  return v;
}

typedef __attribute__((ext_vector_type(2))) __bf16 bf16x2;

// pack two f32 -> u32 of two bf16 (RNE)
#if __has_builtin(__builtin_amdgcn_cvt_pk_bf16_f32)
__device__ __forceinline__ u32 pk2bf(float a, float b){
  union { bf16x2 v; u32 u; } r;
  r.v = __builtin_amdgcn_cvt_pk_bf16_f32(a, b);
  return r.u;
}
#else
__device__ __forceinline__ u32 pk2bf(float a, float b){
  return (u32)f2bf(a) | ((u32)f2bf(b) << 16);
}
#endif

// ---------- MFMA plumbing (16x16x32 bf16) ----------
// A-frag: lane holds A[m=lane&15][k=(lane>>4)*8 + j], j=0..7  (8 bf16 = uint4)
// B-frag: lane holds B[k=(lane>>4)*8 + j][n=lane&15]
// C/D   : reg r at row=(lane>>4)*4+r, col=lane&15
typedef __attribute__((ext_vector_type(8))) short bfrag8;
typedef __attribute__((ext_vector_type(4))) float f4_t;
union FragU { uint4 u; bfrag8 s; };

__device__ __forceinline__ f4_t mfma16(FragU a, FragU b, f4_t c){
  return __builtin_amdgcn_mfma_f32_16x16x32_bf16(a.s, b.s, c, 0, 0, 0);
}

// GEMM core v2: 64M x 128N tile, 4 waves; ntBase selects this wave's 2 N-tiles.
// A (64Mx32K per kt) staged in LDS (double-buffered, one barrier/kt); B frags from global.
template <typename AL>
__device__ __forceinline__ void gemm_core2(int K32, const uint4* __restrict__ Bpack,
                                           int ntBase, f4_t (&acc)[4][2], AL aload){
  __shared__ __align__(16) uint4 As[2][256];
  const int tid = threadIdx.x;
  const int lane = tid & 63;
  const uint4* Bp0 = Bpack + ((size_t)ntBase * K32) * 64 + lane;
  const uint4* Bp1 = Bp0 + (size_t)K32 * 64;
  int buf = 0;
  for (int kt = 0; kt < K32; kt++){
    FragU b0, b1;
    b0.u = Bp0[kt * 64];
    b1.u = Bp1[kt * 64];
    As[buf][tid] = aload(kt);
    __syncthreads();
    FragU a0, a1, a2, a3;
    a0.u = As[buf][lane];
    a1.u = As[buf][64 + lane];
    a2.u = As[buf][128 + lane];
    a3.u = As[buf][192 + lane];
    acc[0][0] = mfma16(a0, b0, acc[0][0]); acc[0][1] = mfma16(a0, b1, acc[0][1]);
    acc[1][0] = mfma16(a1, b0, acc[1][0]); acc[1][1] = mfma16(a1, b1, acc[1][1]);
    acc[2][0] = mfma16(a2, b0, acc[2][0]); acc[2][1] = mfma16(a2, b1, acc[2][1]);
    acc[3][0] = mfma16(a3, b0, acc[3][0]); acc[3][1] = mfma16(a3, b1, acc[3][1]);
    buf ^= 1;
  }
}

// ---------- prep: pack weight matrix into B-fragment-layout bf16 chunks ----------
// chunk c: nt=c/(K32*64), kt=(c/64)%K32, l=c&63 -> holds B[k=kt*32+(l>>4)*8+j][n=nt*16+(l&15)]
// trans=0: B[k][n] = W[k*N+n] ; trans=1: B[k][n] = W[n*K+k]
__global__ __launch_bounds__(256) void k_packB(const float* __restrict__ W, u16* __restrict__ out,
                                               int K, int N, int trans){
  int c = blockIdx.x * 256 + threadIdx.x;
  int K32 = K >> 5;
  int total = (N >> 4) * K32 * 64;
  if (c >= total) return;
  int l = c & 63;
  int rem = c >> 6;
  int kt = rem % K32, nt = rem / K32;
  int n = nt * 16 + (l & 15);
  int kb = kt * 32 + (l >> 4) * 8;
  u32 ov[4];
  #pragma unroll
  for (int j2 = 0; j2 < 4; j2++){
    int k = kb + j2 * 2;
    float f0 = trans ? W[(size_t)n * K + k]     : W[(size_t)k * N + n];
    float f1 = trans ? W[(size_t)n * K + k + 1] : W[(size_t)(k + 1) * N + n];
    ov[j2] = pk2bf(f0, f1);
  }
  uint4 o; o.x = ov[0]; o.y = ov[1]; o.z = ov[2]; o.w = ov[3];
  *(uint4*)(out + (size_t)c * 8) = o;
}

// ---------- CSR build (chain graph, in-degree <= 3) ----------
__global__ void k_csr(const int* __restrict__ src, const int* __restrict__ dst, int E,
                      int* __restrict__ deg, int* __restrict__ insrc){
  int tid = threadIdx.x;
  for (int i = tid; i < NN; i += 256) deg[i] = 0;
  for (int i = tid; i < NN * 4; i += 256) insrc[i] = 0;
  __syncthreads();
  for (int e = tid; e < E; e += 256){
    int d = dst[e];
    int slot = atomicAdd(&deg[d], 1);
    if (slot < 4) insrc[d * 4 + slot] = src[e];
  }
}

// ---------- GEMM 1 (MFMA): x0 = concat(emb_p[p], emb_aff[aff]) @ W_affcat + b ; K=512, N=256, f32 out
__global__ __launch_bounds__(256) void k_affcat_m(
    const float* __restrict__ emb_p, const float* __restrict__ emb_aff,
    const int* __restrict__ p, const int* __restrict__ aff,
    const uint4* __restrict__ Bpack, const float* __restrict__ bias, float* __restrict__ C){
  const int tid = threadIdx.x;
  const int mBase = blockIdx.x * 64, nBase = blockIdx.y * 128;
  const int ls = tid & 63;
  const int gm = mBase + (tid >> 6) * 16 + (ls & 15);
  const int kqoff = (ls >> 4) * 8;
  const float* rp = emb_p + (size_t)p[gm] * 256 + kqoff;
  const float* ra = emb_aff + (size_t)aff[gm] * 256 + kqoff;
  f4_t acc[4][2] = {};
  gemm_core2(16, Bpack, blockIdx.y * 8 + ((tid >> 6) << 1), acc, [&](int kt) -> uint4 {
    int kb = kt * 32;
    const float* s = (kb < 256) ? (rp + kb) : (ra + kb - 256);
    float4 v0 = *(const float4*)s;
    float4 v1 = *(const float4*)(s + 4);
    uint4 o; o.x = pk2bf(v0.x, v0.y); o.y = pk2bf(v0.z, v0.w);
    o.z = pk2bf(v1.x, v1.y); o.w = pk2bf(v1.z, v1.w);
    return o;
  });
  const int wave = tid >> 6, lane = tid & 63;
  const int rb = (lane >> 4) << 2;
  const int cbase = nBase + wave * 32 + (lane & 15);
  float b0 = bias[cbase], b1 = bias[cbase + 16];
  #pragma unroll
  for (int i = 0; i < 4; i++)
    #pragma unroll
    for (int r = 0; r < 4; r++){
      int row = mBase + i * 16 + rb + r;
      C[(size_t)row * 256 + cbase]      = acc[i][0][r] + b0;
      C[(size_t)row * 256 + cbase + 16] = acc[i][1][r] + b1;
    }
}

// ---------- GEMM 2 (MFMA): h1 = x0 @ W_g1 ; K=256, N=1024, bf16 out
__global__ __launch_bounds__(256) void k_h1_m(const float* __restrict__ A,
                                              const uint4* __restrict__ Bpack,
                                              u16* __restrict__ Cb){
  const int tid = threadIdx.x;
  const int mBase = blockIdx.x * 64, nBase = blockIdx.y * 128;
  const int ls = tid & 63;
  const int gm = mBase + (tid >> 6) * 16 + (ls & 15);
  const float* ra = A + (size_t)gm * 256 + (ls >> 4) * 8;
  f4_t acc[4][2] = {};
  gemm_core2(8, Bpack, blockIdx.y * 8 + ((tid >> 6) << 1), acc, [&](int kt) -> uint4 {
    const float* s = ra + kt * 32;
    float4 v0 = *(const float4*)s;
    float4 v1 = *(const float4*)(s + 4);
    uint4 o; o.x = pk2bf(v0.x, v0.y); o.y = pk2bf(v0.z, v0.w);
    o.z = pk2bf(v1.x, v1.y); o.w = pk2bf(v1.z, v1.w);
    return o;
  });
  const int wave = tid >> 6, lane = tid & 63;
  const int rb = (lane >> 4) << 2;
  const int cbase = nBase + wave * 32 + (lane & 15);
  #pragma unroll
  for (int i = 0; i < 4; i++)
    #pragma unroll
    for (int r = 0; r < 4; r++){
      int row = mBase + i * 16 + rb + r;
      Cb[(size_t)row * 1024 + cbase]      = f2bf(acc[i][0][r]);
      Cb[(size_t)row * 1024 + cbase + 16] = f2bf(acc[i][1][r]);
    }
}

// ---------- GEMM 3 (MFMA): h2 = g1out @ W_g2 ; K=1024, N=256, f32 out ; A already bf16
__global__ __launch_bounds__(256) void k_h2_m(const u16* __restrict__ A,
                                              const uint4* __restrict__ Bpack,
                                              float* __restrict__ C){
  const int tid = threadIdx.x;
  const int mBase = blockIdx.x * 64, nBase = blockIdx.y * 128;
  const int ls = tid & 63;
  const int gm = mBase + (tid >> 6) * 16 + (ls & 15);
  const u16* ra = A + (size_t)gm * 1024 + (ls >> 4) * 8;
  f4_t acc[4][2] = {};
  gemm_core2(32, Bpack, blockIdx.y * 8 + ((tid >> 6) << 1), acc, [&](int kt) -> uint4 {
    return *(const uint4*)(ra + kt * 32);
  });
  const int wave = tid >> 6, lane = tid & 63;
  const int rb = (lane >> 4) << 2;
  const int cbase = nBase + wave * 32 + (lane & 15);
  #pragma unroll
  for (int i = 0; i < 4; i++)
    #pragma unroll
    for (int r = 0; r < 4; r++){
      int row = mBase + i * 16 + rb + r;
      C[(size_t)row * 256 + cbase]      = acc[i][0][r];
      C[(size_t)row * 256 + cbase + 16] = acc[i][1][r];
    }
}

// ---------- GEMM 4 (MFMA): gates = concat(p,q,r,x2) @ W_ih^T + bih + bhh ; K=1024, N=1024, bf16 out
__global__ __launch_bounds__(256) void k_gates_m(
    const float* __restrict__ emb_p, const float* __restrict__ emb_q, const float* __restrict__ emb_r,
    const int* __restrict__ p, const int* __restrict__ q, const int* __restrict__ r,
    const float* __restrict__ x2, const uint4* __restrict__ Bpack,
    const float* __restrict__ bih, const float* __restrict__ bhh, u16* __restrict__ Cb){
  const int tid = threadIdx.x;
  const int mBase = blockIdx.x * 64, nBase = blockIdx.y * 128;
  const int ls = tid & 63;
  const int gm = mBase + (tid >> 6) * 16 + (ls & 15);
  const int kqoff = (ls >> 4) * 8;
  const float* s0 = emb_p + (size_t)p[gm] * 256 + kqoff;
  const float* s1 = emb_q + (size_t)q[gm] * 256 + kqoff;
  const float* s2 = emb_r + (size_t)r[gm] * 256 + kqoff;
  const float* s3 = x2 + (size_t)gm * 256 + kqoff;
  f4_t acc[4][2] = {};
  gemm_core2(32, Bpack, blockIdx.y * 8 + ((tid >> 6) << 1), acc, [&](int kt) -> uint4 {
    int kb = kt * 32;
    int seg = kb >> 8, ko = kb & 255;
    const float* s = (seg == 0) ? s0 : ((seg == 1) ? s1 : ((seg == 2) ? s2 : s3));
    float4 v0 = *(const float4*)(s + ko);
    float4 v1 = *(const float4*)(s + ko + 4);
    uint4 o; o.x = pk2bf(v0.x, v0.y); o.y = pk2bf(v0.z, v0.w);
    o.z = pk2bf(v1.x, v1.y); o.w = pk2bf(v1.z, v1.w);
    return o;
  });
  const int wave = tid >> 6, lane = tid & 63;
  const int rb = (lane >> 4) << 2;
  const int cbase = nBase + wave * 32 + (lane & 15);
  float b0 = bih[cbase] + bhh[cbase];
  float b1 = bih[cbase + 16] + bhh[cbase + 16];
  #pragma unroll
  for (int i = 0; i < 4; i++)
    #pragma unroll
    for (int r2 = 0; r2 < 4; r2++){
      int row = mBase + i * 16 + rb + r2;
      Cb[(size_t)row * 1024 + cbase]      = f2bf(acc[i][0][r2] + b0);
      Cb[(size_t)row * 1024 + cbase + 16] = f2bf(acc[i][1][r2] + b1);
    }
}

// ---------- repack gates row [m=b*NN+n][1024] -> per-lane uint4 stream ----------
// G2 uint4 index: m*128 + w*16 + uc ; u16 slot (0..7) = P*4 + g holds
// gates[m][g*256 + w*32 + P*16 + uc]. One block per row m; LDS-staged.
__global__ __launch_bounds__(256) void k_repack2(const u16* __restrict__ gates,
                                                 u16* __restrict__ G2){
  __shared__ __align__(16) u16 staged[1024];
  const int tid = threadIdx.x;
  const size_t m = blockIdx.x;
  const u32* row32 = (const u32*)(gates + m * 1024);
  ((u32*)staged)[tid]       = row32[tid];
  ((u32*)staged)[tid + 256] = row32[tid + 256];
  __syncthreads();
  if (tid < 128){
    const int w = tid >> 4, uc = tid & 15;
    u32 vw[4];
    #pragma unroll
    for (int j = 0; j < 4; j++){
      const int P = j >> 1, glo = (j & 1) * 2;
      const u16 lo = staged[glo * 256 + w * 32 + P * 16 + uc];
      const u16 hi = staged[(glo + 1) * 256 + w * 32 + P * 16 + uc];
      vw[j] = (u32)lo | ((u32)hi << 16);
    }
    uint4 o; o.x = vw[0]; o.y = vw[1]; o.z = vw[2]; o.w = vw[3];
    *(uint4*)(G2 + (m * 128 + (size_t)tid) * 8) = o;
  }
}

// ---------- es/ed: per (m,h) dots of h-row with a_src / a_dst ; one wave per w = m*H+h
__global__ __launch_bounds__(256) void k_esed(
    const u16* __restrict__ hb, const float* __restrict__ hf,
    const float* __restrict__ asrc, const float* __restrict__ adst,
    float* __restrict__ es, float* __restrict__ ed, int Hm1, int Fo){
  int w = blockIdx.x * 4 + (threadIdx.x >> 6);
  int lane = threadIdx.x & 63;
  int h = w & Hm1;
  size_t base = (size_t)w * Fo;
  float s = 0.f, d = 0.f;
  for (int f = lane; f < Fo; f += 64){
    float hv = hb ? bf2f(hb[base + f]) : hf[base + f];
    s += hv * asrc[h * Fo + f];
    d += hv * adst[h * Fo + f];
  }
  s = wred(s); d = wred(d);
  if (!lane){ es[w] = s; ed[w] = d; }
}

// ---------- GAT aggregation: segment softmax (deg<=3) + weighted sum + bias (+ELU)
__global__ __launch_bounds__(256) void k_gatagg(
    const u16* __restrict__ hb, const float* __restrict__ hf,
    const float* __restrict__ es, const float* __restrict__ ed,
    const int* __restrict__ deg, const int* __restrict__ insrc,
    const float* __restrict__ bias, u16* __restrict__ outb, float* __restrict__ outf,
    int H, int foShift, int HFo, int do_elu){
  int m = blockIdx.x;
  int b = m / NN;
  int n = m - b * NN;
  int dg = deg[n];
  int s0 = insrc[n * 4 + 0];
  int s1 = insrc[n * 4 + 1];
  int s2 = insrc[n * 4 + 2];
  int rowBase = b * NN;
  for (int c = threadIdx.x; c < HFo; c += 256){
    int h = c >> foShift;
    float edv = ed[(size_t)m * H + h];
    float sc0 = es[(size_t)(rowBase + s0) * H + h] + edv;
    sc0 = (sc0 >= 0.f) ? sc0 : 0.2f * sc0;
    float sc1 = 0.f, sc2 = 0.f, mx = sc0;
    if (dg > 1){ sc1 = es[(size_t)(rowBase + s1) * H + h] + edv; sc1 = (sc1 >= 0.f) ? sc1 : 0.2f * sc1; mx = fmaxf(mx, sc1); }
    if (dg > 2){ sc2 = es[(size_t)(rowBase + s2) * H + h] + edv; sc2 = (sc2 >= 0.f) ? sc2 : 0.2f * sc2; mx = fmaxf(mx, sc2); }
    float e0 = __expf(sc0 - mx), e1 = 0.f, e2 = 0.f;
    if (dg > 1) e1 = __expf(sc1 - mx);
    if (dg > 2) e2 = __expf(sc2 - mx);
    float inv = 1.f / (e0 + e1 + e2);
    size_t c0 = (size_t)(rowBase + s0) * HFo + c;
    float acc = e0 * (hb ? bf2f(hb[c0]) : hf[c0]);
    if (dg > 1){ size_t c1 = (size_t)(rowBase + s1) * HFo + c; acc += e1 * (hb ? bf2f(hb[c1]) : hf[c1]); }
    if (dg > 2){ size_t c2 = (size_t)(rowBase + s2) * HFo + c; acc += e2 * (hb ? bf2f(hb[c2]) : hf[c2]); }
    acc *= inv;
    float o = acc + bias[c];
    if (do_elu) o = (o > 0.f) ? o : (__expf(o) - 1.f);
    if (outb) outb[(size_t)m * HFo + c] = f2bf(o);
    else      outf[(size_t)m * HFo + c] = o;
  }
}

// ---------- LSTM recurrence v17 (MFMA, 64 blocks = 1 batch/CU) ----------
// Round-6 post-mortem: v16 was VALU-bound (67% on its 4 active CUs) — all gate
// sigma/tanh for 64x256 cells ran on 4 CUs because MFMA M=16 forced 16
// batches/block. v17: 1 batch/block, 64 blocks. MFMA rows are REDUNDANT (all
// lanes broadcast-read the same h chunk -> all 16 M-rows identical; row 0 used).
// Per-SIMD MFMA unchanged (620cy); per-CU gate VALU drops 16x (2 ci/thread).
// Weights: v16's exact proven tiering per wave — 32 frags in reg/AGPR, 17 in
// LDS (136KB), 15 streamed from L2 via 6-deep ring with >=6-phase issue lead.
// h: 512B double-buffered LDS, broadcast reads (no swizzle needed).
// Sync: one lgkmcnt(0) + raw s_barrier + sched_barrier(0) per step (proven).
#define WREG 32
#define WLDS 17
__global__ __launch_bounds__(512)
__attribute__((amdgpu_waves_per_eu(2, 2)))
void k_lstm(const u16* __restrict__ g2,       // gates in k_repack2 layout
            const uint4* __restrict__ bph,    // packed W_hh^T B-frags (K=256,N=1024)
            float* __restrict__ h_all){
  __shared__ __align__(16) uint4 wlds[8][WLDS][64];   // 136 KB weight tail
  __shared__ __align__(16) u16 hsh[2][256];           // 1 KB double-buffered h
  const int b = blockIdx.x, tid = threadIdx.x;
  const int w = tid >> 6, lane = tid & 63;
  const int uc = lane & 15, oct = lane >> 4;
  if (tid < 64) ((u32*)hsh[1])[tid & 63] = 0u;        // h(-1) = 0 (128 u32 total; 2x coverage ok)
  if (tid < 128) ((u32*)hsh[1])[tid] = 0u;

  // ---- resident weights (v16 tiering; frag(P,g,kc) at bph[((g*16+w*2+P)*8+kc)*64+lane]) ----
  uint4 wreg[WREG];
  #pragma unroll
  for (int kc = 0; kc < 8; kc++)
    #pragma unroll
    for (int g = 0; g < 3; g++)     // pass0 g0..g2
      wreg[kc * 3 + g] = bph[(size_t)(((g * 16 + w * 2) * 8 + kc) * 64) + lane];
  wreg[24] = bph[(size_t)(((48 + w * 2) * 8) * 64) + lane];   // pass0 g3 kc0
  #pragma unroll
  for (int kc = 1; kc < 8; kc++)    // pass1 g2 kc1..7
    wreg[24 + kc] = bph[(size_t)(((32 + w * 2 + 1) * 8 + kc) * 64) + lane];
  #pragma unroll
  for (int kc = 0; kc < 8; kc++){
    wlds[w][kc][lane]     = bph[(size_t)(((w * 2 + 1) * 8 + kc) * 64) + lane];        // pass1 g0
    wlds[w][8 + kc][lane] = bph[(size_t)(((16 + w * 2 + 1) * 8 + kc) * 64) + lane];   // pass1 g1
  }
  wlds[w][16][lane] = bph[(size_t)(((32 + w * 2 + 1) * 8) * 64) + lane];              // pass1 g2 kc0

  // ---- stream base: frag(P, g3, kc) = sp[(P*8 + kc)*64]; sid s <-> offset (s+1)*64
  const uint4* sp = bph + (size_t)(((48 + w * 2) * 8) * 64) + lane;

  // gate stream: one uint4 per (b,n,w,lane-col); all octs load the same 16B (dedup in L2)
  const uint4* g0p = (const uint4*)g2 + (size_t)b * NN * 128 + w * 16 + uc;
  uint4 G0q = *g0p;
  g0p += 128;

  const size_t hofs0 = ((size_t)b * NN) * 256 + (size_t)w * 32 + uc;
  float cst[2] = {0.f, 0.f};

  // ring prologue for step 0: sids 0..5
  uint4 wstr[6];
  #pragma unroll
  for (int s = 0; s < 6; s++) wstr[s] = sp[(s + 1) * 64];
  __syncthreads();

  #pragma unroll 1
  for (int n = 0; n < NN; n++){
    const char* hrd = (const char*)hsh[(n + 1) & 1];   // h(n-1)
    char* hwr = (char*)hsh[n & 1];                     // h(n)
    float hv2[2];
    #pragma unroll
    for (int P = 0; P < 2; P++){
      f4_t acc[4] = {};
      #pragma unroll
      for (int kc = 0; kc < 8; kc++){
        const int ph = P * 8 + kc;          // 0..15, compile-time
        FragU a;
        a.u = *(const uint4*)(hrd + (u32)(kc * 64 + oct * 16));   // broadcast within oct
        #pragma unroll
        for (int g = 0; g < 4; g++){
          FragU bb;
          if (P == 0){
            if (g < 3)            bb.u = wreg[kc * 3 + g];
            else if (kc == 0)     bb.u = wreg[24];
            else                  bb.u = wstr[(ph - 1) % 6];
          } else {
            if (g == 0)           bb.u = wlds[w][kc][lane];
            else if (g == 1)      bb.u = wlds[w][8 + kc][lane];
            else if (g == 2)      bb.u = (kc == 0) ? wlds[w][16][lane] : wreg[24 + kc];
            else                  bb.u = wstr[(ph - 1) % 6];
          }
          acc[g] = mfma16(a, bb, acc[g]);
        }
        if (ph >= 1 && ph <= 9)
          wstr[(ph + 5) % 6] = sp[(ph + 6) * 64];
      }
      if (P == 1){
        #pragma unroll
        for (int s = 0; s < 6; s++) wstr[s] = sp[(s + 1) * 64];
      }
      // gate math (all octs compute identically; row 0 of acc): unit u = w*32+P*16+uc
      float gv[4];
      #pragma unroll
      for (int g = 0; g < 4; g++){
        const int wi = P * 2 + (g >> 1);
        const u32 uw = (wi == 0) ? G0q.x : (wi == 1) ? G0q.y : (wi == 2) ? G0q.z : G0q.w;
        gv[g] = acc[g][0] + ((g & 1) ? hi16(uw) : lo16(uw));
      }
      const float cv = sigf(gv[1]) * cst[P] + sigf(gv[0]) * tanh_(gv[2]);
      cst[P] = cv;
      hv2[P] = sigf(gv[3]) * tanh_(cv);
    }
    // oct 0 publishes h(n) chunk + h_all
    if (oct == 0){
      #pragma unroll
      for (int P = 0; P < 2; P++){
        const int u = w * 32 + P * 16 + uc;
        *(u16*)(hwr + u * 2) = f2bf(hv2[P]);
        h_all[hofs0 + (size_t)n * 256 + P * 16] = hv2[P];
      }
    }
    // issue next step's gate load (consumed one full step later)
    if (n + 1 < NN){
      G0q = *g0p;
      g0p += 128;
    }
    // publish h(n): drain LDS ops, barrier (no vmcnt drain), fence scheduling
    asm volatile("s_waitcnt lgkmcnt(0)" ::: "memory");
    __builtin_amdgcn_s_barrier();
    __builtin_amdgcn_sched_barrier(0);
  }
}

// ---------- final: y = sigmoid(concat(h, qn_emb, pn_emb) @ W_out + b_out) ; one wave per row
__global__ __launch_bounds__(256) void k_out(const float* __restrict__ h_all,
    const float* __restrict__ emb_q, const float* __restrict__ emb_p,
    const int* __restrict__ qn, const int* __restrict__ pn,
    const float* __restrict__ Wo, const float* __restrict__ bo, float* __restrict__ y){
  int m = blockIdx.x * 4 + (threadIdx.x >> 6);
  int lane = threadIdx.x & 63;
  const float* hr = h_all + (size_t)m * 256;
  const float* rq = emb_q + (size_t)qn[m] * 256;
  const float* rp = emb_p + (size_t)pn[m] * 256;
  float acc = 0.f;
  #pragma unroll
  for (int f = 0; f < 256; f += 64){
    int d = f + lane;
    acc += hr[d] * Wo[d];
    acc += rq[d] * Wo[256 + d];
    acc += rp[d] * Wo[512 + d];
  }
  acc = wred(acc);
  if (!lane) y[m] = sigf(acc + bo[0]);
}

// ---------- launch ----------
extern "C" void kernel_launch(void* const* d_in, const int* in_sizes, int n_in,
                              void* d_out, int out_size, void* d_ws, size_t ws_size,
                              hipStream_t stream){
  (void)n_in; (void)out_size; (void)ws_size;
  const int* p    = (const int*)d_in[1];
  const int* q    = (const int*)d_in[2];
  const int* r    = (const int*)d_in[3];
  const int* aff  = (const int*)d_in[4];
  const int* qn   = (const int*)d_in[5];
  const int* pn   = (const int*)d_in[6];
  const int* src  = (const int*)d_in[7];
  const int* dst  = (const int*)d_in[8];
  const float* emb_p  = (const float*)d_in[9];
  const float* emb_q  = (const float*)d_in[10];
  const float* emb_r  = (const float*)d_in[11];
  const float* emb_aff= (const float*)d_in[12];
  const float* W_aff  = (const float*)d_in[13];
  const float* b_aff  = (const float*)d_in[14];
  const float* W_g1   = (const float*)d_in[15];
  const float* a_s1   = (const float*)d_in[16];
  const float* a_d1   = (const float*)d_in[17];
  const float* b_g1   = (const float*)d_in[18];
  const float* W_g2   = (const float*)d_in[19];
  const float* a_s2   = (const float*)d_in[20];
  const float* a_d2   = (const float*)d_in[21];
  const float* b_g2   = (const float*)d_in[22];
  const float* W_ih   = (const float*)d_in[23];
  const float* W_hh   = (const float*)d_in[24];
  const float* b_ih   = (const float*)d_in[25];
  const float* b_hh   = (const float*)d_in[26];
  const float* W_out  = (const float*)d_in[27];
  const float* b_out  = (const float*)d_in[28];
  const int E = in_sizes[7];

  char* ws = (char*)d_ws;
  size_t off = 0;
  auto alloc = [&](size_t bytes){ size_t ret = off; off += (bytes + 255) & ~(size_t)255; return ret; };
  size_t o_bigA = alloc((size_t)MTOT * 1024 * 2);   // h1 bf16 -> gates bf16 (row layout)
  size_t o_bigB = alloc((size_t)MTOT * 1024 * 2);   // g1out bf16 -> x2 f32 -> G2 (lstm layout)
  size_t o_buf3 = alloc((size_t)MTOT * 256 * 4);    // x0 -> h2 -> h_all
  size_t o_es1 = alloc((size_t)MTOT * 8 * 4);
  size_t o_ed1 = alloc((size_t)MTOT * 8 * 4);
  size_t o_es2 = alloc((size_t)MTOT * 4);
  size_t o_ed2 = alloc((size_t)MTOT * 4);
  size_t o_whh = alloc((size_t)32768 * 16);      // W_hh^T B-frag pack (K=256,N=1024)
  size_t o_deg = alloc(512 * 4);
  size_t o_ins = alloc((size_t)NN * 4 * 4);
  size_t o_bpih  = alloc((size_t)131072 * 16);   // W_ih^T pack (K=1024,N=1024)
  size_t o_bpg1  = alloc((size_t)32768 * 16);    // W_g1 pack (K=256,N=1024)
  size_t o_bpg2  = alloc((size_t)32768 * 16);    // W_g2 pack (K=1024,N=256)
  size_t o_bpaff = alloc((size_t)16384 * 16);    // W_affcat pack (K=512,N=256)

  u16*   h1    = (u16*)(ws + o_bigA);
  u16*   gates = (u16*)(ws + o_bigA);
  u16*   g1out = (u16*)(ws + o_bigB);
  float* x2    = (float*)(ws + o_bigB);
  u16*   G2    = (u16*)(ws + o_bigB);
  float* x0    = (float*)(ws + o_buf3);
  float* h2    = (float*)(ws + o_buf3);
  float* h_all = (float*)(ws + o_buf3);
  float* es1   = (float*)(ws + o_es1);
  float* ed1   = (float*)(ws + o_ed1);
  float* es2   = (float*)(ws + o_es2);
  float* ed2   = (float*)(ws + o_ed2);
  u16*   bphh  = (u16*)(ws + o_whh);
  int*   degp  = (int*)(ws + o_deg);
  int*   insp  = (int*)(ws + o_ins);
  u16*   bpih  = (u16*)(ws + o_bpih);
  u16*   bpg1  = (u16*)(ws + o_bpg1);
  u16*   bpg2  = (u16*)(ws + o_bpg2);
  u16*   bpaff = (u16*)(ws + o_bpaff);

  k_csr<<<1, 256, 0, stream>>>(src, dst, E, degp, insp);
  k_packB<<<128, 256, 0, stream>>>(W_hh, bphh, 256, 1024, 1);
  k_packB<<<512, 256, 0, stream>>>(W_ih, bpih, 1024, 1024, 1);
  k_packB<<<128, 256, 0, stream>>>(W_g1, bpg1, 256, 1024, 0);
  k_packB<<<128, 256, 0, stream>>>(W_g2, bpg2, 1024, 256, 0);
  k_packB<<<64, 256, 0, stream>>>(W_aff, bpaff, 512, 256, 0);

  k_affcat_m<<<dim3(NN, 2), 256, 0, stream>>>(emb_p, emb_aff, p, aff,
                                              (const uint4*)bpaff, b_aff, x0);
  k_h1_m<<<dim3(NN, 8), 256, 0, stream>>>(x0, (const uint4*)bpg1, h1);
  k_esed<<<(MTOT * 8) / 4, 256, 0, stream>>>(h1, nullptr, a_s1, a_d1, es1, ed1, 7, 128);
  k_gatagg<<<MTOT, 256, 0, stream>>>(h1, nullptr, es1, ed1, degp, insp, b_g1,
                                     g1out, nullptr, 8, 7, 1024, 1);
  k_h2_m<<<dim3(NN, 2), 256, 0, stream>>>(g1out, (const uint4*)bpg2, h2);
  k_esed<<<MTOT / 4, 256, 0, stream>>>(nullptr, h2, a_s2, a_d2, es2, ed2, 0, 256);
  k_gatagg<<<MTOT, 256, 0, stream>>>(nullptr, h2, es2, ed2, degp, insp, b_g2,
                                     nullptr, x2, 1, 8, 256, 0);
  k_gates_m<<<dim3(NN, 8), 256, 0, stream>>>(emb_p, emb_q, emb_r, p, q, r, x2,
                                             (const uint4*)bpih, b_ih, b_hh, gates);
  k_repack2<<<MTOT, 256, 0, stream>>>(gates, G2);
  k_lstm<<<BB, 512, 0, stream>>>(G2, (const uint4*)bphh, h_all);
  k_out<<<MTOT / 4, 256, 0, stream>>>(h_all, emb_q, emb_p, qn, pn, W_out, b_out, (float*)d_out);
}

// Round 8
// 1480.718 us; speedup vs baseline: 4.2674x; 1.0328x over previous
//
#include <hip/hip_runtime.h>
#include <hip/hip_bf16.h>

typedef unsigned int u32;
typedef unsigned short u16;

#define MTOT 31936      // B*N = 64*499
#define NN 499
#define BB 64

// ---------- helpers ----------
__device__ __forceinline__ float lo16(u32 u){ return __uint_as_float(u << 16); }
__device__ __forceinline__ float hi16(u32 u){ return __uint_as_float(u & 0xffff0000u); }
__device__ __forceinline__ float bf2f(u16 u){ return __uint_as_float(((u32)u) << 16); }
__device__ __forceinline__ u16 f2bf(float f){
  u32 x = __float_as_uint(f);
  u32 r = (x + 0x7fffu + ((x >> 16) & 1u)) >> 16;   // RNE
  return (u16)r;
}
__device__ __forceinline__ float sigf(float x){ return 1.f / (1.f + __expf(-x)); }
__device__ __forceinline__ float tanh_(float x){ return 2.f * sigf(2.f * x) - 1.f; }
__device__ __forceinline__ float wred(float v){
  #pragma unroll
  for (int off = 32; off; off >>= 1) v += __shfl_down(v, off, 64);
  return v;
}

typedef __attribute__((ext_vector_type(2))) __bf16 bf16x2;

// pack two f32 -> u32 of two bf16 (RNE)
#if __has_builtin(__builtin_amdgcn_cvt_pk_bf16_f32)
__device__ __forceinline__ u32 pk2bf(float a, float b){
  union { bf16x2 v; u32 u; } r;
  r.v = __builtin_amdgcn_cvt_pk_bf16_f32(a, b);
  return r.u;
}
#else
__device__ __forceinline__ u32 pk2bf(float a, float b){
  return (u32)f2bf(a) | ((u32)f2bf(b) << 16);
}
#endif

// address-space types for global_load_lds
typedef __attribute__((address_space(1))) void AS1void;
typedef __attribute__((address_space(3))) void AS3void;

// ---------- MFMA plumbing (16x16x32 bf16) ----------
// A-frag: lane holds A[m=lane&15][k=(lane>>4)*8 + j], j=0..7  (8 bf16 = uint4)
// B-frag: lane holds B[k=(lane>>4)*8 + j][n=lane&15]
// C/D   : reg r at row=(lane>>4)*4+r, col=lane&15
typedef __attribute__((ext_vector_type(8))) short bfrag8;
typedef __attribute__((ext_vector_type(4))) float f4_t;
union FragU { uint4 u; bfrag8 s; };

__device__ __forceinline__ f4_t mfma16(FragU a, FragU b, f4_t c){
  return __builtin_amdgcn_mfma_f32_16x16x32_bf16(a.s, b.s, c, 0, 0, 0);
}

// GEMM core v3: 64M x 128N tile, 4 waves; ntBase selects this wave's 2 N-tiles.
// A tile (64Mx32K per kt) staged via global_load_lds width=16 from BF16 sources
// (aaddr(kt) = per-lane global address of this lane's 16B A-frag chunk). LDS dest
// is wave-uniform base + lane*16 (HW rule). __syncthreads' vmcnt(0) drain is the
// completion wait. Double-buffered with one barrier/kt (write buf^1 while others
// still read buf is safe; reads of buf gated by the barrier).
template <typename AP>
__device__ __forceinline__ void gemm_core3(int K32, const uint4* __restrict__ Bpack,
                                           int ntBase, f4_t (&acc)[4][2], AP aaddr){
  __shared__ __align__(16) uint4 As[2][256];
  const int tid = threadIdx.x;
  const int wave = tid >> 6, lane = tid & 63;
  const uint4* Bp0 = Bpack + ((size_t)ntBase * K32) * 64 + lane;
  const uint4* Bp1 = Bp0 + (size_t)K32 * 64;
  int buf = 0;
  for (int kt = 0; kt < K32; kt++){
    FragU b0, b1;
    b0.u = Bp0[kt * 64];
    b1.u = Bp1[kt * 64];
    __builtin_amdgcn_global_load_lds((AS1void*)aaddr(kt),
                                     (AS3void*)&As[buf][wave * 64], 16, 0, 0);
    __syncthreads();
    FragU a0, a1, a2, a3;
    a0.u = As[buf][lane];
    a1.u = As[buf][64 + lane];
    a2.u = As[buf][128 + lane];
    a3.u = As[buf][192 + lane];
    acc[0][0] = mfma16(a0, b0, acc[0][0]); acc[0][1] = mfma16(a0, b1, acc[0][1]);
    acc[1][0] = mfma16(a1, b0, acc[1][0]); acc[1][1] = mfma16(a1, b1, acc[1][1]);
    acc[2][0] = mfma16(a2, b0, acc[2][0]); acc[2][1] = mfma16(a2, b1, acc[2][1]);
    acc[3][0] = mfma16(a3, b0, acc[3][0]); acc[3][1] = mfma16(a3, b1, acc[3][1]);
    buf ^= 1;
  }
}

// ---------- prep: f32 -> bf16 elementwise pack (embedding tables) ----------
__global__ __launch_bounds__(256) void k_packE(const float* __restrict__ in,
                                               u16* __restrict__ out, int n4){
  int i = blockIdx.x * 256 + threadIdx.x;
  if (i >= n4) return;
  float4 v = ((const float4*)in)[i];
  uint2 o; o.x = pk2bf(v.x, v.y); o.y = pk2bf(v.z, v.w);
  ((uint2*)out)[i] = o;
}

// ---------- prep: pack weight matrix into B-fragment-layout bf16 chunks ----------
// chunk c: nt=c/(K32*64), kt=(c/64)%K32, l=c&63 -> holds B[k=kt*32+(l>>4)*8+j][n=nt*16+(l&15)]
// trans=0: B[k][n] = W[k*N+n] ; trans=1: B[k][n] = W[n*K+k]
__global__ __launch_bounds__(256) void k_packB(const float* __restrict__ W, u16* __restrict__ out,
                                               int K, int N, int trans){
  int c = blockIdx.x * 256 + threadIdx.x;
  int K32 = K >> 5;
  int total = (N >> 4) * K32 * 64;
  if (c >= total) return;
  int l = c & 63;
  int rem = c >> 6;
  int kt = rem % K32, nt = rem / K32;
  int n = nt * 16 + (l & 15);
  int kb = kt * 32 + (l >> 4) * 8;
  u32 ov[4];
  #pragma unroll
  for (int j2 = 0; j2 < 4; j2++){
    int k = kb + j2 * 2;
    float f0 = trans ? W[(size_t)n * K + k]     : W[(size_t)k * N + n];
    float f1 = trans ? W[(size_t)n * K + k + 1] : W[(size_t)(k + 1) * N + n];
    ov[j2] = pk2bf(f0, f1);
  }
  uint4 o; o.x = ov[0]; o.y = ov[1]; o.z = ov[2]; o.w = ov[3];
  *(uint4*)(out + (size_t)c * 8) = o;
}

// ---------- CSR build (chain graph, in-degree <= 3) ----------
__global__ void k_csr(const int* __restrict__ src, const int* __restrict__ dst, int E,
                      int* __restrict__ deg, int* __restrict__ insrc){
  int tid = threadIdx.x;
  for (int i = tid; i < NN; i += 256) deg[i] = 0;
  for (int i = tid; i < NN * 4; i += 256) insrc[i] = 0;
  __syncthreads();
  for (int e = tid; e < E; e += 256){
    int d = dst[e];
    int slot = atomicAdd(&deg[d], 1);
    if (slot < 4) insrc[d * 4 + slot] = src[e];
  }
}

// ---------- GEMM 1 (MFMA): x0 = concat(emb_p[p], emb_aff[aff]) @ W_affcat + b ; K=512, N=256, bf16 out
__global__ __launch_bounds__(256) void k_affcat_m(
    const u16* __restrict__ emb_pb, const u16* __restrict__ emb_ab,
    const int* __restrict__ p, const int* __restrict__ aff,
    const uint4* __restrict__ Bpack, const float* __restrict__ bias, u16* __restrict__ Cb){
  const int tid = threadIdx.x;
  const int mBase = blockIdx.x * 64, nBase = blockIdx.y * 128;
  const int ls = tid & 63;
  const int gm = mBase + (tid >> 6) * 16 + (ls & 15);
  const int kqoff = (ls >> 4) * 8;
  const u16* rp = emb_pb + (size_t)p[gm] * 256 + kqoff;
  const u16* ra = emb_ab + (size_t)aff[gm] * 256 + kqoff;
  f4_t acc[4][2] = {};
  gemm_core3(16, Bpack, blockIdx.y * 8 + ((tid >> 6) << 1), acc, [&](int kt) -> const void* {
    int kb = kt * 32;
    return (kb < 256) ? (const void*)(rp + kb) : (const void*)(ra + kb - 256);
  });
  const int wave = tid >> 6, lane = tid & 63;
  const int rb = (lane >> 4) << 2;
  const int cbase = nBase + wave * 32 + (lane & 15);
  float b0 = bias[cbase], b1 = bias[cbase + 16];
  #pragma unroll
  for (int i = 0; i < 4; i++)
    #pragma unroll
    for (int r = 0; r < 4; r++){
      int row = mBase + i * 16 + rb + r;
      Cb[(size_t)row * 256 + cbase]      = f2bf(acc[i][0][r] + b0);
      Cb[(size_t)row * 256 + cbase + 16] = f2bf(acc[i][1][r] + b1);
    }
}

// ---------- GEMM 2 (MFMA): h1 = x0 @ W_g1 ; K=256, N=1024, bf16 out ; A bf16
__global__ __launch_bounds__(256) void k_h1_m(const u16* __restrict__ A,
                                              const uint4* __restrict__ Bpack,
                                              u16* __restrict__ Cb){
  const int tid = threadIdx.x;
  const int mBase = blockIdx.x * 64, nBase = blockIdx.y * 128;
  const int ls = tid & 63;
  const int gm = mBase + (tid >> 6) * 16 + (ls & 15);
  const u16* ra = A + (size_t)gm * 256 + (ls >> 4) * 8;
  f4_t acc[4][2] = {};
  gemm_core3(8, Bpack, blockIdx.y * 8 + ((tid >> 6) << 1), acc, [&](int kt) -> const void* {
    return (const void*)(ra + kt * 32);
  });
  const int wave = tid >> 6, lane = tid & 63;
  const int rb = (lane >> 4) << 2;
  const int cbase = nBase + wave * 32 + (lane & 15);
  #pragma unroll
  for (int i = 0; i < 4; i++)
    #pragma unroll
    for (int r = 0; r < 4; r++){
      int row = mBase + i * 16 + rb + r;
      Cb[(size_t)row * 1024 + cbase]      = f2bf(acc[i][0][r]);
      Cb[(size_t)row * 1024 + cbase + 16] = f2bf(acc[i][1][r]);
    }
}

// ---------- GEMM 3 (MFMA): h2 = g1out @ W_g2 ; K=1024, N=256, f32 out ; A bf16
__global__ __launch_bounds__(256) void k_h2_m(const u16* __restrict__ A,
                                              const uint4* __restrict__ Bpack,
                                              float* __restrict__ C){
  const int tid = threadIdx.x;
  const int mBase = blockIdx.x * 64, nBase = blockIdx.y * 128;
  const int ls = tid & 63;
  const int gm = mBase + (tid >> 6) * 16 + (ls & 15);
  const u16* ra = A + (size_t)gm * 1024 + (ls >> 4) * 8;
  f4_t acc[4][2] = {};
  gemm_core3(32, Bpack, blockIdx.y * 8 + ((tid >> 6) << 1), acc, [&](int kt) -> const void* {
    return (const void*)(ra + kt * 32);
  });
  const int wave = tid >> 6, lane = tid & 63;
  const int rb = (lane >> 4) << 2;
  const int cbase = nBase + wave * 32 + (lane & 15);
  #pragma unroll
  for (int i = 0; i < 4; i++)
    #pragma unroll
    for (int r = 0; r < 4; r++){
      int row = mBase + i * 16 + rb + r;
      C[(size_t)row * 256 + cbase]      = acc[i][0][r];
      C[(size_t)row * 256 + cbase + 16] = acc[i][1][r];
    }
}

// ---------- GEMM 4 (MFMA): gates = concat(p,q,r,x2) @ W_ih^T + bih + bhh ; K=1024, N=1024, bf16 out
__global__ __launch_bounds__(256) void k_gates_m(
    const u16* __restrict__ emb_pb, const u16* __restrict__ emb_qb, const u16* __restrict__ emb_rb,
    const int* __restrict__ p, const int* __restrict__ q, const int* __restrict__ r,
    const u16* __restrict__ x2b, const uint4* __restrict__ Bpack,
    const float* __restrict__ bih, const float* __restrict__ bhh, u16* __restrict__ Cb){
  const int tid = threadIdx.x;
  const int mBase = blockIdx.x * 64, nBase = blockIdx.y * 128;
  const int ls = tid & 63;
  const int gm = mBase + (tid >> 6) * 16 + (ls & 15);
  const int kqoff = (ls >> 4) * 8;
  const u16* s0 = emb_pb + (size_t)p[gm] * 256 + kqoff;
  const u16* s1 = emb_qb + (size_t)q[gm] * 256 + kqoff;
  const u16* s2 = emb_rb + (size_t)r[gm] * 256 + kqoff;
  const u16* s3 = x2b + (size_t)gm * 256 + kqoff;
  f4_t acc[4][2] = {};
  gemm_core3(32, Bpack, blockIdx.y * 8 + ((tid >> 6) << 1), acc, [&](int kt) -> const void* {
    int kb = kt * 32;
    int seg = kb >> 8, ko = kb & 255;
    const u16* s = (seg == 0) ? s0 : ((seg == 1) ? s1 : ((seg == 2) ? s2 : s3));
    return (const void*)(s + ko);
  });
  const int wave = tid >> 6, lane = tid & 63;
  const int rb = (lane >> 4) << 2;
  const int cbase = nBase + wave * 32 + (lane & 15);
  float b0 = bih[cbase] + bhh[cbase];
  float b1 = bih[cbase + 16] + bhh[cbase + 16];
  #pragma unroll
  for (int i = 0; i < 4; i++)
    #pragma unroll
    for (int r2 = 0; r2 < 4; r2++){
      int row = mBase + i * 16 + rb + r2;
      Cb[(size_t)row * 1024 + cbase]      = f2bf(acc[i][0][r2] + b0);
      Cb[(size_t)row * 1024 + cbase + 16] = f2bf(acc[i][1][r2] + b1);
    }
}

// ---------- repack gates row [m=b*NN+n][1024] -> per-lane uint4 stream ----------
// G2 uint4 index: m*128 + w*16 + uc ; u16 slot (0..7) = P*4 + g holds
// gates[m][g*256 + w*32 + P*16 + uc]. One block per row m; LDS-staged.
__global__ __launch_bounds__(256) void k_repack2(const u16* __restrict__ gates,
                                                 u16* __restrict__ G2){
  __shared__ __align__(16) u16 staged[1024];
  const int tid = threadIdx.x;
  const size_t m = blockIdx.x;
  const u32* row32 = (const u32*)(gates + m * 1024);
  ((u32*)staged)[tid]       = row32[tid];
  ((u32*)staged)[tid + 256] = row32[tid + 256];
  __syncthreads();
  if (tid < 128){
    const int w = tid >> 4, uc = tid & 15;
    u32 vw[4];
    #pragma unroll
    for (int j = 0; j < 4; j++){
      const int P = j >> 1, glo = (j & 1) * 2;
      const u16 lo = staged[glo * 256 + w * 32 + P * 16 + uc];
      const u16 hi = staged[(glo + 1) * 256 + w * 32 + P * 16 + uc];
      vw[j] = (u32)lo | ((u32)hi << 16);
    }
    uint4 o; o.x = vw[0]; o.y = vw[1]; o.z = vw[2]; o.w = vw[3];
    *(uint4*)(G2 + (m * 128 + (size_t)tid) * 8) = o;
  }
}

// ---------- es/ed: per (m,h) dots of h-row with a_src / a_dst ; one wave per w = m*H+h
__global__ __launch_bounds__(256) void k_esed(
    const u16* __restrict__ hb, const float* __restrict__ hf,
    const float* __restrict__ asrc, const float* __restrict__ adst,
    float* __restrict__ es, float* __restrict__ ed, int Hm1, int Fo){
  int w = blockIdx.x * 4 + (threadIdx.x >> 6);
  int lane = threadIdx.x & 63;
  int h = w & Hm1;
  size_t base = (size_t)w * Fo;
  float s = 0.f, d = 0.f;
  for (int f = lane; f < Fo; f += 64){
    float hv = hb ? bf2f(hb[base + f]) : hf[base + f];
    s += hv * asrc[h * Fo + f];
    d += hv * adst[h * Fo + f];
  }
  s = wred(s); d = wred(d);
  if (!lane){ es[w] = s; ed[w] = d; }
}

// ---------- GAT aggregation: segment softmax (deg<=3) + weighted sum + bias (+ELU)
__global__ __launch_bounds__(256) void k_gatagg(
    const u16* __restrict__ hb, const float* __restrict__ hf,
    const float* __restrict__ es, const float* __restrict__ ed,
    const int* __restrict__ deg, const int* __restrict__ insrc,
    const float* __restrict__ bias, u16* __restrict__ outb, float* __restrict__ outf,
    int H, int foShift, int HFo, int do_elu){
  int m = blockIdx.x;
  int b = m / NN;
  int n = m - b * NN;
  int dg = deg[n];
  int s0 = insrc[n * 4 + 0];
  int s1 = insrc[n * 4 + 1];
  int s2 = insrc[n * 4 + 2];
  int rowBase = b * NN;
  for (int c = threadIdx.x; c < HFo; c += 256){
    int h = c >> foShift;
    float edv = ed[(size_t)m * H + h];
    float sc0 = es[(size_t)(rowBase + s0) * H + h] + edv;
    sc0 = (sc0 >= 0.f) ? sc0 : 0.2f * sc0;
    float sc1 = 0.f, sc2 = 0.f, mx = sc0;
    if (dg > 1){ sc1 = es[(size_t)(rowBase + s1) * H + h] + edv; sc1 = (sc1 >= 0.f) ? sc1 : 0.2f * sc1; mx = fmaxf(mx, sc1); }
    if (dg > 2){ sc2 = es[(size_t)(rowBase + s2) * H + h] + edv; sc2 = (sc2 >= 0.f) ? sc2 : 0.2f * sc2; mx = fmaxf(mx, sc2); }
    float e0 = __expf(sc0 - mx), e1 = 0.f, e2 = 0.f;
    if (dg > 1) e1 = __expf(sc1 - mx);
    if (dg > 2) e2 = __expf(sc2 - mx);
    float inv = 1.f / (e0 + e1 + e2);
    size_t c0 = (size_t)(rowBase + s0) * HFo + c;
    float acc = e0 * (hb ? bf2f(hb[c0]) : hf[c0]);
    if (dg > 1){ size_t c1 = (size_t)(rowBase + s1) * HFo + c; acc += e1 * (hb ? bf2f(hb[c1]) : hf[c1]); }
    if (dg > 2){ size_t c2 = (size_t)(rowBase + s2) * HFo + c; acc += e2 * (hb ? bf2f(hb[c2]) : hf[c2]); }
    acc *= inv;
    float o = acc + bias[c];
    if (do_elu) o = (o > 0.f) ? o : (__expf(o) - 1.f);
    if (outb) outb[(size_t)m * HFo + c] = f2bf(o);
    else      outf[(size_t)m * HFo + c] = o;
  }
}

// ---------- LSTM recurrence v18 (MFMA, 64 blocks, merged passes) ----------
// v17 (passed, 849us) measured: MfmaUtil 50% on active CUs, step 4080cy vs MFMA
// floor 2483cy (128 MFMA/SIMD x 19.4cy). v18 merges the two passes into one
// dense 16-phase MFMA block (acc[8], 8 independent chains) with a single
// gate-math tail — removes the P0->P1 boundary bubble (wlds-read latency) and
// one gate tail from the critical path. Math, indices, ring schedule, weight
// tiering (32 reg + 17 LDS + 15 streamed, 6-deep ring) identical to v17.
#define WREG 32
#define WLDS 17
__global__ __launch_bounds__(512)
__attribute__((amdgpu_waves_per_eu(2, 2)))
void k_lstm(const u16* __restrict__ g2,       // gates in k_repack2 layout
            const uint4* __restrict__ bph,    // packed W_hh^T B-frags (K=256,N=1024)
            float* __restrict__ h_all){
  __shared__ __align__(16) uint4 wlds[8][WLDS][64];   // 136 KB weight tail
  __shared__ __align__(16) u16 hsh[2][256];           // 1 KB double-buffered h
  const int b = blockIdx.x, tid = threadIdx.x;
  const int w = tid >> 6, lane = tid & 63;
  const int uc = lane & 15, oct = lane >> 4;
  if (tid < 128) ((u32*)hsh[1])[tid] = 0u;            // h(-1) = 0

  // ---- resident weights (frag(P,g,kc) at bph[((g*16+w*2+P)*8+kc)*64+lane]) ----
  uint4 wreg[WREG];
  #pragma unroll
  for (int kc = 0; kc < 8; kc++)
    #pragma unroll
    for (int g = 0; g < 3; g++)     // pass0 g0..g2
      wreg[kc * 3 + g] = bph[(size_t)(((g * 16 + w * 2) * 8 + kc) * 64) + lane];
  wreg[24] = bph[(size_t)(((48 + w * 2) * 8) * 64) + lane];   // pass0 g3 kc0
  #pragma unroll
  for (int kc = 1; kc < 8; kc++)    // pass1 g2 kc1..7
    wreg[24 + kc] = bph[(size_t)(((32 + w * 2 + 1) * 8 + kc) * 64) + lane];
  #pragma unroll
  for (int kc = 0; kc < 8; kc++){
    wlds[w][kc][lane]     = bph[(size_t)(((w * 2 + 1) * 8 + kc) * 64) + lane];        // pass1 g0
    wlds[w][8 + kc][lane] = bph[(size_t)(((16 + w * 2 + 1) * 8 + kc) * 64) + lane];   // pass1 g1
  }
  wlds[w][16][lane] = bph[(size_t)(((32 + w * 2 + 1) * 8) * 64) + lane];              // pass1 g2 kc0

  // ---- stream base: frag(P, g3, kc) = sp[(P*8 + kc)*64]; sid s <-> offset (s+1)*64
  const uint4* sp = bph + (size_t)(((48 + w * 2) * 8) * 64) + lane;

  // gate stream: one uint4 per (b,n,w,lane-col); octs load the same 16B
  const uint4* g0p = (const uint4*)g2 + (size_t)b * NN * 128 + w * 16 + uc;
  uint4 G0q = *g0p;
  g0p += 128;

  const size_t hofs0 = ((size_t)b * NN) * 256 + (size_t)w * 32 + uc;
  float cst[2] = {0.f, 0.f};

  // ring prologue for step 0: sids 0..5
  uint4 wstr[6];
  #pragma unroll
  for (int s = 0; s < 6; s++) wstr[s] = sp[(s + 1) * 64];
  __syncthreads();

  #pragma unroll 1
  for (int n = 0; n < NN; n++){
    const char* hrd = (const char*)hsh[(n + 1) & 1];   // h(n-1)
    char* hwr = (char*)hsh[n & 1];                     // h(n)
    f4_t acc[8] = {};
    #pragma unroll
    for (int ph = 0; ph < 16; ph++){
      const int P = ph >> 3, kc = ph & 7;
      FragU a;
      a.u = *(const uint4*)(hrd + (u32)(kc * 64 + oct * 16));   // broadcast within oct
      #pragma unroll
      for (int g = 0; g < 4; g++){
        FragU bb;
        if (P == 0){
          if (g < 3)            bb.u = wreg[kc * 3 + g];
          else if (kc == 0)     bb.u = wreg[24];
          else                  bb.u = wstr[(ph - 1) % 6];
        } else {
          if (g == 0)           bb.u = wlds[w][kc][lane];
          else if (g == 1)      bb.u = wlds[w][8 + kc][lane];
          else if (g == 2)      bb.u = (kc == 0) ? wlds[w][16][lane] : wreg[24 + kc];
          else                  bb.u = wstr[(ph - 1) % 6];
        }
        acc[P * 4 + g] = mfma16(a, bb, acc[P * 4 + g]);
      }
      if (ph >= 1 && ph <= 9)
        wstr[(ph + 5) % 6] = sp[(ph + 6) * 64];
    }
    // next step's ring prologue (sids 0..5): issued before the gate tail
    #pragma unroll
    for (int s = 0; s < 6; s++) wstr[s] = sp[(s + 1) * 64];
    // gate math (all octs identical; row 0 of acc): unit u = w*32+P*16+uc
    float hv2[2];
    #pragma unroll
    for (int P = 0; P < 2; P++){
      float gv[4];
      #pragma unroll
      for (int g = 0; g < 4; g++){
        const int wi = P * 2 + (g >> 1);
        const u32 uw = (wi == 0) ? G0q.x : (wi == 1) ? G0q.y : (wi == 2) ? G0q.z : G0q.w;
        gv[g] = acc[P * 4 + g][0] + ((g & 1) ? hi16(uw) : lo16(uw));
      }
      const float cv = sigf(gv[1]) * cst[P] + sigf(gv[0]) * tanh_(gv[2]);
      cst[P] = cv;
      hv2[P] = sigf(gv[3]) * tanh_(cv);
    }
    // oct 0 publishes h(n) chunk + h_all
    if (oct == 0){
      #pragma unroll
      for (int P = 0; P < 2; P++){
        const int u = w * 32 + P * 16 + uc;
        *(u16*)(hwr + u * 2) = f2bf(hv2[P]);
        h_all[hofs0 + (size_t)n * 256 + P * 16] = hv2[P];
      }
    }
    // issue next step's gate load (consumed one full step later)
    if (n + 1 < NN){
      G0q = *g0p;
      g0p += 128;
    }
    // publish h(n): drain LDS ops, barrier (no vmcnt drain), fence scheduling
    asm volatile("s_waitcnt lgkmcnt(0)" ::: "memory");
    __builtin_amdgcn_s_barrier();
    __builtin_amdgcn_sched_barrier(0);
  }
}

// ---------- final: y = sigmoid(concat(h, qn_emb, pn_emb) @ W_out + b_out) ; one wave per row
__global__ __launch_bounds__(256) void k_out(const float* __restrict__ h_all,
    const float* __restrict__ emb_q, const float* __restrict__ emb_p,
    const int* __restrict__ qn, const int* __restrict__ pn,
    const float* __restrict__ Wo, const float* __restrict__ bo, float* __restrict__ y){
  int m = blockIdx.x * 4 + (threadIdx.x >> 6);
  int lane = threadIdx.x & 63;
  const float* hr = h_all + (size_t)m * 256;
  const float* rq = emb_q + (size_t)qn[m] * 256;
  const float* rp = emb_p + (size_t)pn[m] * 256;
  float acc = 0.f;
  #pragma unroll
  for (int f = 0; f < 256; f += 64){
    int d = f + lane;
    acc += hr[d] * Wo[d];
    acc += rq[d] * Wo[256 + d];
    acc += rp[d] * Wo[512 + d];
  }
  acc = wred(acc);
  if (!lane) y[m] = sigf(acc + bo[0]);
}

// ---------- launch ----------
extern "C" void kernel_launch(void* const* d_in, const int* in_sizes, int n_in,
                              void* d_out, int out_size, void* d_ws, size_t ws_size,
                              hipStream_t stream){
  (void)n_in; (void)out_size; (void)ws_size;
  const int* p    = (const int*)d_in[1];
  const int* q    = (const int*)d_in[2];
  const int* r    = (const int*)d_in[3];
  const int* aff  = (const int*)d_in[4];
  const int* qn   = (const int*)d_in[5];
  const int* pn   = (const int*)d_in[6];
  const int* src  = (const int*)d_in[7];
  const int* dst  = (const int*)d_in[8];
  const float* emb_p  = (const float*)d_in[9];
  const float* emb_q  = (const float*)d_in[10];
  const float* emb_r  = (const float*)d_in[11];
  const float* emb_aff= (const float*)d_in[12];
  const float* W_aff  = (const float*)d_in[13];
  const float* b_aff  = (const float*)d_in[14];
  const float* W_g1   = (const float*)d_in[15];
  const float* a_s1   = (const float*)d_in[16];
  const float* a_d1   = (const float*)d_in[17];
  const float* b_g1   = (const float*)d_in[18];
  const float* W_g2   = (const float*)d_in[19];
  const float* a_s2   = (const float*)d_in[20];
  const float* a_d2   = (const float*)d_in[21];
  const float* b_g2   = (const float*)d_in[22];
  const float* W_ih   = (const float*)d_in[23];
  const float* W_hh   = (const float*)d_in[24];
  const float* b_ih   = (const float*)d_in[25];
  const float* b_hh   = (const float*)d_in[26];
  const float* W_out  = (const float*)d_in[27];
  const float* b_out  = (const float*)d_in[28];
  const int E = in_sizes[7];

  char* ws = (char*)d_ws;
  size_t off = 0;
  auto alloc = [&](size_t bytes){ size_t ret = off; off += (bytes + 255) & ~(size_t)255; return ret; };
  size_t o_bigA = alloc((size_t)MTOT * 1024 * 2);   // h1 bf16 -> gates bf16 (row layout)
  size_t o_bigB = alloc((size_t)MTOT * 1024 * 2);   // g1out bf16 -> x2b bf16 -> G2 (lstm layout)
  size_t o_buf3 = alloc((size_t)MTOT * 256 * 4);    // x0b bf16 -> h2 f32 -> h_all f32
  size_t o_es1 = alloc((size_t)MTOT * 8 * 4);
  size_t o_ed1 = alloc((size_t)MTOT * 8 * 4);
  size_t o_es2 = alloc((size_t)MTOT * 4);
  size_t o_ed2 = alloc((size_t)MTOT * 4);
  size_t o_whh = alloc((size_t)32768 * 16);      // W_hh^T B-frag pack (K=256,N=1024)
  size_t o_deg = alloc(512 * 4);
  size_t o_ins = alloc((size_t)NN * 4 * 4);
  size_t o_bpih  = alloc((size_t)131072 * 16);   // W_ih^T pack (K=1024,N=1024)
  size_t o_bpg1  = alloc((size_t)32768 * 16);    // W_g1 pack (K=256,N=1024)
  size_t o_bpg2  = alloc((size_t)32768 * 16);    // W_g2 pack (K=1024,N=256)
  size_t o_bpaff = alloc((size_t)16384 * 16);    // W_affcat pack (K=512,N=256)
  size_t o_ebp = alloc((size_t)10001 * 256 * 2); // emb_p bf16
  size_t o_ebq = alloc((size_t)2001 * 256 * 2);  // emb_q bf16
  size_t o_ebr = alloc((size_t)2 * 256 * 2);     // emb_r bf16
  size_t o_eba = alloc((size_t)11 * 256 * 2);    // emb_aff bf16

  u16*   h1    = (u16*)(ws + o_bigA);
  u16*   gates = (u16*)(ws + o_bigA);
  u16*   g1out = (u16*)(ws + o_bigB);
  u16*   x2b   = (u16*)(ws + o_bigB);
  u16*   G2    = (u16*)(ws + o_bigB);
  u16*   x0b   = (u16*)(ws + o_buf3);
  float* h2    = (float*)(ws + o_buf3);
  float* h_all = (float*)(ws + o_buf3);
  float* es1   = (float*)(ws + o_es1);
  float* ed1   = (float*)(ws + o_ed1);
  float* es2   = (float*)(ws + o_es2);
  float* ed2   = (float*)(ws + o_ed2);
  u16*   bphh  = (u16*)(ws + o_whh);
  int*   degp  = (int*)(ws + o_deg);
  int*   insp  = (int*)(ws + o_ins);
  u16*   bpih  = (u16*)(ws + o_bpih);
  u16*   bpg1  = (u16*)(ws + o_bpg1);
  u16*   bpg2  = (u16*)(ws + o_bpg2);
  u16*   bpaff = (u16*)(ws + o_bpaff);
  u16*   ebp   = (u16*)(ws + o_ebp);
  u16*   ebq   = (u16*)(ws + o_ebq);
  u16*   ebr   = (u16*)(ws + o_ebr);
  u16*   eba   = (u16*)(ws + o_eba);

  k_csr<<<1, 256, 0, stream>>>(src, dst, E, degp, insp);
  k_packB<<<128, 256, 0, stream>>>(W_hh, bphh, 256, 1024, 1);
  k_packB<<<512, 256, 0, stream>>>(W_ih, bpih, 1024, 1024, 1);
  k_packB<<<128, 256, 0, stream>>>(W_g1, bpg1, 256, 1024, 0);
  k_packB<<<128, 256, 0, stream>>>(W_g2, bpg2, 1024, 256, 0);
  k_packB<<<64, 256, 0, stream>>>(W_aff, bpaff, 512, 256, 0);
  k_packE<<<2501, 256, 0, stream>>>(emb_p, ebp, 10001 * 64);
  k_packE<<<501, 256, 0, stream>>>(emb_q, ebq, 2001 * 64);
  k_packE<<<1, 256, 0, stream>>>(emb_r, ebr, 2 * 64);
  k_packE<<<3, 256, 0, stream>>>(emb_aff, eba, 11 * 64);

  k_affcat_m<<<dim3(NN, 2), 256, 0, stream>>>(ebp, eba, p, aff,
                                              (const uint4*)bpaff, b_aff, x0b);
  k_h1_m<<<dim3(NN, 8), 256, 0, stream>>>(x0b, (const uint4*)bpg1, h1);
  k_esed<<<(MTOT * 8) / 4, 256, 0, stream>>>(h1, nullptr, a_s1, a_d1, es1, ed1, 7, 128);
  k_gatagg<<<MTOT, 256, 0, stream>>>(h1, nullptr, es1, ed1, degp, insp, b_g1,
                                     g1out, nullptr, 8, 7, 1024, 1);
  k_h2_m<<<dim3(NN, 2), 256, 0, stream>>>(g1out, (const uint4*)bpg2, h2);
  k_esed<<<MTOT / 4, 256, 0, stream>>>(nullptr, h2, a_s2, a_d2, es2, ed2, 0, 256);
  k_gatagg<<<MTOT, 256, 0, stream>>>(nullptr, h2, es2, ed2, degp, insp, b_g2,
                                     x2b, nullptr, 1, 8, 256, 0);
  k_gates_m<<<dim3(NN, 8), 256, 0, stream>>>(ebp, ebq, ebr, p, q, r, x2b,
                                             (const uint4*)bpih, b_ih, b_hh, gates);
  k_repack2<<<MTOT, 256, 0, stream>>>(gates, G2);
  k_lstm<<<BB, 512, 0, stream>>>(G2, (const uint4*)bphh, h_all);
  k_out<<<MTOT / 4, 256, 0, stream>>>(h_all, emb_q, emb_p, qn, pn, W_out, b_out, (float*)d_out);
}